// Round 16
// baseline (169.709 us; speedup 1.0000x reference)
//
#include <hip/hip_runtime.h>
#include <stdint.h>

#define NB 4
#define NS 2048
#define ND 1024
#define NH 16
#define NM 8192   // NB*NS

typedef __attribute__((ext_vector_type(4))) float          f32x4;
typedef __attribute__((ext_vector_type(8))) __bf16         bf16x8;
typedef __attribute__((ext_vector_type(8))) unsigned short u16x8;
typedef __attribute__((ext_vector_type(4))) unsigned short u16x4;

static __device__ __forceinline__ unsigned short f2bf(float f) {
  unsigned u = __builtin_bit_cast(unsigned, f);
  return (unsigned short)((u + 0x7fffu + ((u >> 16) & 1u)) >> 16);
}

#if __has_builtin(__builtin_amdgcn_exp2f)
#define EX2(x) __builtin_amdgcn_exp2f(x)
#else
#define EX2(x) __expf((x) * 0.69314718056f)
#endif
#if __has_builtin(__builtin_amdgcn_rcpf)
#define RCP(x) __builtin_amdgcn_rcpf(x)
#else
#define RCP(x) (1.0f / (x))
#endif

static __device__ __forceinline__ unsigned cvtpk(float lo, float hi) {
  unsigned r;
  asm("v_cvt_pk_bf16_f32 %0, %1, %2" : "=v"(r) : "v"(lo), "v"(hi));
  return r;
}

static __device__ __forceinline__ float max3f(float a, float b, float c) {
  return fmaxf(fmaxf(a, b), c);   // clang fuses to v_max3_f32
}

static __device__ __forceinline__ void gld_lds16(const void* g, void* l) {
  __builtin_amdgcn_global_load_lds((const __attribute__((address_space(1))) void*)g,
                                   (__attribute__((address_space(3))) void*)l, 16, 0, 0);
}

// ---------------------------------------------------------------- cast f32->bf16
// single dispatch: blocks [0,8192) = x, [8192,12288) = the four weights
__global__ __launch_bounds__(256) void cast_all(
    const float* __restrict__ x,
    const float* __restrict__ Wq, const float* __restrict__ Wk,
    const float* __restrict__ Wv, const float* __restrict__ Wo,
    unsigned short* __restrict__ xb,
    unsigned short* __restrict__ Wqb, unsigned short* __restrict__ Wkb,
    unsigned short* __restrict__ Wvb, unsigned short* __restrict__ Wob)
{
  const int bx = blockIdx.x;
  const float* in;
  unsigned short* out;
  int i;
  if (bx < 8192) {
    in = x; out = xb; i = bx * 256 + threadIdx.x;
  } else {
    const int z  = (bx - 8192) >> 10;
    const int lb = (bx - 8192) & 1023;
    in  = (z == 0) ? Wq  : (z == 1) ? Wk  : (z == 2) ? Wv  : Wo;
    out = (z == 0) ? Wqb : (z == 1) ? Wkb : (z == 2) ? Wvb : Wob;
    i = lb * 256 + threadIdx.x;
  }
  f32x4 v = ((const f32x4*)in)[i];
  u16x4 o;
#pragma unroll
  for (int e = 0; e < 4; ++e) o[e] = f2bf(v[e]);
  ((u16x4*)out)[i] = o;
}

// ---------------------------------------------------------------- fused QKV GEMM
// 128m x 64n x 3z tile, SAME 2-phase dbuf loop, but 8 waves (512 thr, 4m x 2n)
// so LDS 40KB -> 4 WG/CU and ALL 1024 WGs are resident in ONE round (the 3-WG
// config ran 768 + 256-tail = ~1.5x quantization loss). acc 3x2x2 f32x4 = 48
// regs, ~100 total <= 128 budget at (512,4).
__global__ __launch_bounds__(512, 4) void gemm_qkv_fused(
    const unsigned short* __restrict__ A,      // xb [8192][1024]
    const unsigned short* __restrict__ Wqkv,   // Wq,Wk,Wv contiguous [1024][1024]
    const int* __restrict__ tp,
    unsigned short* __restrict__ QKt,          // Qt,Kt contiguous [8192][1024]
    unsigned short* __restrict__ Vt2)          // [64 bh][64 d][2048 s]
{
  union SMem {
    struct { unsigned short As[2][128 * 32]; unsigned short Bs[2][3][64 * 32]; } g;
    unsigned short Tt[64][136];  // V-transpose scratch (pad 136)
  };
  __shared__ SMem sm;

  const int tid  = threadIdx.x;              // 0..511
  const int wid  = tid >> 6, lane = tid & 63;
  const int ln   = lane & 15, kg = lane >> 4;
  const int wr   = wid >> 1,  wc = wid & 1;  // 4m x 2n wave grid
  const int m0   = blockIdx.y * 128, n0 = blockIdx.x * 64;

  // A staging: 512 chunks, one per thread: r = tid>>2, slot = tid&3
  const int rA = tid >> 2, sA = tid & 3;
  const int fA = (rA & 3) ^ ((rA >> 2) & 3);
  const unsigned short* gA = A + (size_t)(m0 + rA) * ND + ((sA ^ fA) * 8);
  const int dA = tid * 8;

  // B staging: 3 x 256 chunks. Chunk 1: z = tid>>8 (wave-uniform), cz = tid&255.
  const int z01 = tid >> 8, cB0 = tid & 255;
  const int rB0 = cB0 >> 2, sB0 = cB0 & 3;
  const int fB0 = (rB0 & 3) ^ ((rB0 >> 2) & 3);
  const unsigned short* gB0 =
      Wqkv + (size_t)z01 * ND * ND + (size_t)(n0 + rB0) * ND + ((sB0 ^ fB0) * 8);
  const int dB0 = cB0 * 8;
  // Chunk 2 (threads < 256 only, wave-uniform predicate): z = 2 (Wv)
  const bool hasB1 = (tid < 256);
  const int rB1 = tid >> 2, sB1 = tid & 3;
  const int fB1 = (rB1 & 3) ^ ((rB1 >> 2) & 3);
  const unsigned short* gB1 =
      Wqkv + (size_t)2 * ND * ND + (size_t)(n0 + rB1) * ND + ((sB1 ^ fB1) * 8);
  const int dB1 = tid * 8;

  const int fql = (ln & 3) ^ ((ln >> 2) & 3);
  const int kco = (kg ^ fql) * 8;
  int offA[2], offB[2];
#pragma unroll
  for (int mi = 0; mi < 2; ++mi)
    offA[mi] = (wr * 32 + mi * 16 + ln) * 32 + kco;
#pragma unroll
  for (int nj = 0; nj < 2; ++nj)
    offB[nj] = (wc * 32 + nj * 16 + ln) * 32 + kco;

  f32x4 acc[3][2][2];
#pragma unroll
  for (int z = 0; z < 3; ++z)
#pragma unroll
    for (int mi = 0; mi < 2; ++mi)
#pragma unroll
      for (int nj = 0; nj < 2; ++nj) acc[z][mi][nj] = (f32x4){0.f, 0.f, 0.f, 0.f};

  // prologue: stage k-tile 0 into buf 0
  gld_lds16(gA,  &sm.g.As[0][dA]);
  gld_lds16(gB0, &sm.g.Bs[0][z01][dB0]);
  if (hasB1) gld_lds16(gB1, &sm.g.Bs[0][2][dB1]);
  gA += 32; gB0 += 32; gB1 += 32;
  __syncthreads();

  for (int t = 0; t < 32; ++t) {
    const int buf = t & 1;
    if (t < 31) {
      const int nb = buf ^ 1;
      gld_lds16(gA,  &sm.g.As[nb][dA]);
      gld_lds16(gB0, &sm.g.Bs[nb][z01][dB0]);
      if (hasB1) gld_lds16(gB1, &sm.g.Bs[nb][2][dB1]);
      gA += 32; gB0 += 32; gB1 += 32;
    }
    bf16x8 af[2];
#pragma unroll
    for (int mi = 0; mi < 2; ++mi) af[mi] = *(const bf16x8*)&sm.g.As[buf][offA[mi]];
#pragma unroll
    for (int z = 0; z < 3; ++z) {
      bf16x8 b0 = *(const bf16x8*)&sm.g.Bs[buf][z][offB[0]];
      bf16x8 b1 = *(const bf16x8*)&sm.g.Bs[buf][z][offB[1]];
#pragma unroll
      for (int mi = 0; mi < 2; ++mi) {
        acc[z][mi][0] = __builtin_amdgcn_mfma_f32_16x16x32_bf16(af[mi], b0, acc[z][mi][0], 0, 0, 0);
        acc[z][mi][1] = __builtin_amdgcn_mfma_f32_16x16x32_bf16(af[mi], b1, acc[z][mi][1], 0, 0, 0);
      }
    }
    __syncthreads();
  }

  // ---- V epilogue: transpose in LDS, write Vt2[bh][d][s] coalesced
#pragma unroll
  for (int mi = 0; mi < 2; ++mi)
#pragma unroll
    for (int r = 0; r < 4; ++r) {
      int ml = wr * 32 + mi * 16 + kg * 4 + r;
#pragma unroll
      for (int nj = 0; nj < 2; ++nj) {
        int nl = wc * 32 + nj * 16 + ln;
        sm.Tt[nl][ml] = f2bf(acc[2][mi][nj][r]);
      }
    }
  __syncthreads();
  {
    const int bq = m0 >> 11, s0 = m0 & 2047;
    unsigned short* vdst = Vt2 + ((size_t)(bq * 16 + blockIdx.x) * 64) * NS + s0;
#pragma unroll
    for (int k = 0; k < 2; ++k) {
      int q = tid + k * 512;            // 1024 chunks of 16B (64 d x 16 offs)
      int row = q >> 4, off = q & 15;
      u16x8 v = *(const u16x8*)&sm.Tt[row][off * 8];
      *(u16x8*)(vdst + (size_t)row * NS + off * 8) = v;
    }
  }

  // ---- Q,K epilogue with fused RoPE (invf/sincos hoisted, shared across z)
  float invf[2];
#pragma unroll
  for (int nj = 0; nj < 2; ++nj) {
    int n  = n0 + wc * 32 + nj * 16 + ln;
    int ip = (n & 63) >> 1;
    invf[nj] = __expf(-0.28782313662425572f * (float)ip);
  }
  const float SC_Q = 0.18033688011111543f;   // 0.125 * log2(e), folded into Q
#pragma unroll
  for (int mi = 0; mi < 2; ++mi)
#pragma unroll
    for (int r = 0; r < 4; ++r) {
      int m = m0 + wr * 32 + mi * 16 + kg * 4 + r;
      float pos = (float)tp[m];
#pragma unroll
      for (int nj = 0; nj < 2; ++nj) {
        int n = n0 + wc * 32 + nj * 16 + ln;
        float sn, cs;
        __sincosf(pos * invf[nj], &sn, &cs);
#pragma unroll
        for (int z = 0; z < 2; ++z) {
          float v  = acc[z][mi][nj][r];
          float pv = __shfl_xor(v, 1);
          float outv = (n & 1) ? (pv * sn + v * cs) : (v * cs - pv * sn);
          if (z == 0) outv *= SC_Q;
          QKt[(size_t)z * NM * ND + (size_t)m * ND + n] = f2bf(outv);
        }
      }
    }
}

// ---------------------------------------------------------------- output GEMM
__global__ __launch_bounds__(256, 4) void gemm_out(
    const unsigned short* __restrict__ A,
    const unsigned short* __restrict__ Bw,
    float* __restrict__ C)
{
  __shared__ unsigned short As[2][128 * 32];
  __shared__ unsigned short Bs[2][128 * 32];

  const int tid  = threadIdx.x;
  const int wid  = tid >> 6, lane = tid & 63;
  const int ln   = lane & 15, kg = lane >> 4;
  const int wr   = wid >> 1,  wc = wid & 1;
  const int m0   = blockIdx.y * 128, n0 = blockIdx.x * 128;

  const int r0 = tid >> 2,        s0 = tid & 3;
  const int r1 = (tid + 256) >> 2;
  const int f0 = (r0 & 3) ^ ((r0 >> 2) & 3);
  const int f1 = (r1 & 3) ^ ((r1 >> 2) & 3);

  const unsigned short* gA0 = A  + (size_t)(m0 + r0) * ND + ((s0 ^ f0) * 8);
  const unsigned short* gA1 = A  + (size_t)(m0 + r1) * ND + ((s0 ^ f1) * 8);
  const unsigned short* gB0 = Bw + (size_t)(n0 + r0) * ND + ((s0 ^ f0) * 8);
  const unsigned short* gB1 = Bw + (size_t)(n0 + r1) * ND + ((s0 ^ f1) * 8);

  const int ldsO0 = wid * 512, ldsO1 = 2048 + wid * 512;

  const int fql = (ln & 3) ^ ((ln >> 2) & 3);
  int offA[4], offB[4];
#pragma unroll
  for (int i = 0; i < 4; ++i) {
    offA[i] = (wr * 64 + i * 16 + ln) * 32 + ((kg ^ fql) * 8);
    offB[i] = (wc * 64 + i * 16 + ln) * 32 + ((kg ^ fql) * 8);
  }

  f32x4 acc[4][4];
#pragma unroll
  for (int i = 0; i < 4; ++i)
#pragma unroll
    for (int j = 0; j < 4; ++j) acc[i][j] = (f32x4){0.f, 0.f, 0.f, 0.f};

  gld_lds16(gA0, &As[0][ldsO0]);
  gld_lds16(gA1, &As[0][ldsO1]);
  gld_lds16(gB0, &Bs[0][ldsO0]);
  gld_lds16(gB1, &Bs[0][ldsO1]);
  gA0 += 32; gA1 += 32; gB0 += 32; gB1 += 32;
  __syncthreads();

  for (int t = 0; t < 32; ++t) {
    const int buf = t & 1;
    if (t < 31) {
      const int nb = buf ^ 1;
      gld_lds16(gA0, &As[nb][ldsO0]);
      gld_lds16(gA1, &As[nb][ldsO1]);
      gld_lds16(gB0, &Bs[nb][ldsO0]);
      gld_lds16(gB1, &Bs[nb][ldsO1]);
      gA0 += 32; gA1 += 32; gB0 += 32; gB1 += 32;
    }
    bf16x8 af[4], bfr[4];
#pragma unroll
    for (int i = 0; i < 4; ++i) af[i] = *(const bf16x8*)&As[buf][offA[i]];
#pragma unroll
    for (int j = 0; j < 4; ++j) bfr[j] = *(const bf16x8*)&Bs[buf][offB[j]];
#pragma unroll
    for (int i = 0; i < 4; ++i)
#pragma unroll
      for (int j = 0; j < 4; ++j)
        acc[i][j] = __builtin_amdgcn_mfma_f32_16x16x32_bf16(af[i], bfr[j], acc[i][j], 0, 0, 0);
    __syncthreads();
  }

#pragma unroll
  for (int i = 0; i < 4; ++i)
#pragma unroll
    for (int j = 0; j < 4; ++j)
#pragma unroll
      for (int r = 0; r < 4; ++r) {
        int m = m0 + wr * 64 + i * 16 + kg * 4 + r;
        int n = n0 + wc * 64 + j * 16 + ln;
        C[(size_t)m * ND + n] = acc[i][j][r];
      }
}

// ---------------------------------------------------------------- flash attention
// R14: 8 waves x 16 q-rows, 1024 WGs XCD-grouped, gld_lds dbuf K/V, row-sum via
// ones-MFMA, max3 tree, defer-max, exp2 domain (Q pre-scaled).
__global__ __launch_bounds__(512, 8) void attn_kernel(
    const unsigned short* __restrict__ Q,
    const unsigned short* __restrict__ K,
    const unsigned short* __restrict__ Vt2,
    unsigned short* __restrict__ O)
{
  __shared__ unsigned short Ks[2][64 * 64];
  __shared__ unsigned short Vs[2][64 * 64];
  __shared__ unsigned long long Pw[8][256];   // per-wave 2KB P/O staging

  const int tid = threadIdx.x;
  const int wid = tid >> 6, lane = tid & 63;
  const int ln  = lane & 15, kg = lane >> 4;

  const int flat = blockIdx.x;
  const int xcd  = flat & 7, g = flat >> 3;   // g in 0..127
  const int qb   = 15 - (g >> 3);             // 128-row q-block, longest first
  const int bh   = xcd + ((g & 7) << 3);      // bh % 8 == xcd
  const int b    = bh >> 4, h = bh & 15;

  const size_t base  = (size_t)b * NS * ND + (size_t)h * 64;
  const size_t vbase = (size_t)bh * 64 * NS;

  const int rA = tid >> 3, slA = tid & 7;
  const unsigned short* KgA = K + base + (size_t)rA * ND + ((slA ^ (rA & 7)) * 8);
  const unsigned short* VgA = Vt2 + vbase + (size_t)rA * NS + ((slA ^ (rA & 7)) * 8);
  const int ldsOff = tid * 8;

  char* pwb = (char*)&Pw[wid][0];
  int wb[4];
#pragma unroll
  for (int j = 0; j < 4; ++j)
    wb[j] = ln * 128 + (((2 * j + (kg >> 1)) ^ (ln & 7)) << 4) + ((kg & 1) << 3);
  const int rb0 = ln * 128 + ((kg ^ (ln & 7)) << 4);
  const int rb1 = ln * 128 + (((4 + kg) ^ (ln & 7)) << 4);

  const int nt   = 2 * qb + 2;
  const int q0   = qb * 128 + wid * 16;
  const int qrow = wid * 16 + ln;

  bf16x8 qf[2];
  {
    const unsigned short* qp = Q + base + (size_t)(q0 + ln) * ND + kg * 8;
    qf[0] = *(const bf16x8*)qp;
    qf[1] = *(const bf16x8*)(qp + 32);
  }

  bf16x8 onesf;
  {
    u16x8 t;
#pragma unroll
    for (int e = 0; e < 8; ++e) t[e] = 0x3F80;   // bf16 1.0
    onesf = __builtin_bit_cast(bf16x8, t);
  }

  float m_run = -1e30f;
  f32x4 acc_o[4];
  f32x4 acc_l = (f32x4){0.f, 0.f, 0.f, 0.f};   // ones-row MFMA: l = acc_l[0]
#pragma unroll
  for (int dj = 0; dj < 4; ++dj) acc_o[dj] = (f32x4){0.f, 0.f, 0.f, 0.f};

  gld_lds16(KgA, &Ks[0][ldsOff]);
  gld_lds16(VgA, &Vs[0][ldsOff]);
  __syncthreads();

  for (int t = 0; t < nt; ++t) {
    const int buf = t & 1;
    if (t + 1 < nt) {
      const size_t ko = (size_t)(t + 1) * 64 * ND;
      const int    vo = (t + 1) * 64;
      const int nb = buf ^ 1;
      gld_lds16(KgA + ko, &Ks[nb][ldsOff]);
      gld_lds16(VgA + vo, &Vs[nb][ldsOff]);
    }

    // ---- S^T = K·Q^T (exp2 domain)
    f32x4 st[4];
    __builtin_amdgcn_s_setprio(1);
#pragma unroll
    for (int j = 0; j < 4; ++j) {
      int kvr = j * 16 + ln;
      bf16x8 k0 = *(const bf16x8*)&Ks[buf][kvr * 64 + ((kg ^ (kvr & 7)) * 8)];
      bf16x8 k1 = *(const bf16x8*)&Ks[buf][kvr * 64 + (((4 + kg) ^ (kvr & 7)) * 8)];
      f32x4 z = (f32x4){0.f, 0.f, 0.f, 0.f};
      z = __builtin_amdgcn_mfma_f32_16x16x32_bf16(k0, qf[0], z, 0, 0, 0);
      z = __builtin_amdgcn_mfma_f32_16x16x32_bf16(k1, qf[1], z, 0, 0, 0);
      st[j] = z;
    }
    __builtin_amdgcn_s_setprio(0);

    const int trel = t - 2 * qb;
    if (trel >= 0) {
#pragma unroll
      for (int j = 0; j < 4; ++j)
#pragma unroll
        for (int r = 0; r < 4; ++r)
          if (trel * 64 + 16 * j + 4 * kg + r > qrow) st[j][r] = -1e30f;
    }

    // ---- row max via v_max3 tree
    float t1 = max3f(st[0][0], st[0][1], st[0][2]);
    float t2 = max3f(st[0][3], st[1][0], st[1][1]);
    float t3 = max3f(st[1][2], st[1][3], st[2][0]);
    float t4 = max3f(st[2][1], st[2][2], st[2][3]);
    float t5 = max3f(st[3][0], st[3][1], st[3][2]);
    float mx = fmaxf(max3f(t1, t2, t3), max3f(t4, t5, st[3][3]));
    mx = fmaxf(mx, __shfl_xor(mx, 16));
    mx = fmaxf(mx, __shfl_xor(mx, 32));

    // ---- defer-max rescale (applies to O and l accumulators)
    if (__any(mx > m_run + 11.0f)) {
      float mnew = fmaxf(m_run, mx);
      float alpha = EX2(m_run - mnew);
      m_run = mnew;
#pragma unroll
      for (int r = 0; r < 4; ++r) acc_l[r] *= alpha;
#pragma unroll
      for (int dj = 0; dj < 4; ++dj)
#pragma unroll
        for (int r = 0; r < 4; ++r) acc_o[dj][r] *= alpha;
    }

#pragma unroll
    for (int j = 0; j < 4; ++j)
#pragma unroll
      for (int r = 0; r < 4; ++r) st[j][r] = EX2(st[j][r] - m_run);

#pragma unroll
    for (int j = 0; j < 4; ++j) {
      unsigned w0 = cvtpk(st[j][0], st[j][1]);
      unsigned w1 = cvtpk(st[j][2], st[j][3]);
      *(unsigned long long*)(pwb + wb[j]) =
          (unsigned long long)w0 | ((unsigned long long)w1 << 32);
    }

    asm volatile("s_waitcnt lgkmcnt(0)" ::: "memory");
    __builtin_amdgcn_sched_barrier(0);

    bf16x8 pb0 = *(const bf16x8*)(pwb + rb0);
    bf16x8 pb1 = *(const bf16x8*)(pwb + rb1);
    __builtin_amdgcn_s_setprio(1);
#pragma unroll
    for (int dj = 0; dj < 4; ++dj) {
      int d = dj * 16 + ln;
      bf16x8 vb0 = *(const bf16x8*)&Vs[buf][d * 64 + ((kg ^ (d & 7)) * 8)];
      bf16x8 vb1 = *(const bf16x8*)&Vs[buf][d * 64 + (((4 + kg) ^ (d & 7)) * 8)];
      acc_o[dj] = __builtin_amdgcn_mfma_f32_16x16x32_bf16(vb0, pb0, acc_o[dj], 0, 0, 0);
      acc_o[dj] = __builtin_amdgcn_mfma_f32_16x16x32_bf16(vb1, pb1, acc_o[dj], 0, 0, 0);
    }
    // row-sum on the matrix pipe: every output row of (ones · P^T) = sum_kv P
    acc_l = __builtin_amdgcn_mfma_f32_16x16x32_bf16(onesf, pb0, acc_l, 0, 0, 0);
    acc_l = __builtin_amdgcn_mfma_f32_16x16x32_bf16(onesf, pb1, acc_l, 0, 0, 0);
    __builtin_amdgcn_s_setprio(0);
    __syncthreads();
  }

  asm volatile("s_waitcnt lgkmcnt(0)" ::: "memory");
  float inv = RCP(acc_l[0]);
#pragma unroll
  for (int dj = 0; dj < 4; ++dj) {
    unsigned w0 = cvtpk(acc_o[dj][0] * inv, acc_o[dj][1] * inv);
    unsigned w1 = cvtpk(acc_o[dj][2] * inv, acc_o[dj][3] * inv);
    *(unsigned long long*)(pwb + wb[dj]) =
        (unsigned long long)w0 | ((unsigned long long)w1 << 32);
  }
  asm volatile("s_waitcnt lgkmcnt(0)" ::: "memory");
  __builtin_amdgcn_sched_barrier(0);
  {
    const int orow = lane >> 3, og = lane & 7;
    const int lb = ((og ^ (orow & 7)) << 4);
    u16x8 o0 = *(const u16x8*)(pwb + orow * 128 + lb);
    u16x8 o1 = *(const u16x8*)(pwb + (8 + orow) * 128 + lb);
    *(u16x8*)(O + base + (size_t)(q0 + orow) * ND + og * 8) = o0;
    *(u16x8*)(O + base + (size_t)(q0 + 8 + orow) * ND + og * 8) = o1;
  }
}

// ---------------------------------------------------------------- launcher
extern "C" void kernel_launch(void* const* d_in, const int* in_sizes, int n_in,
                              void* d_out, int out_size, void* d_ws, size_t ws_size,
                              hipStream_t stream) {
  const float* x  = (const float*)d_in[0];
  const int*   tp = (const int*)d_in[1];
  const float* Wq = (const float*)d_in[2];
  const float* Wk = (const float*)d_in[3];
  const float* Wv = (const float*)d_in[4];
  const float* Wo = (const float*)d_in[5];
  float* out = (float*)d_out;

  const size_t MD2 = (size_t)NM * ND * 2;  // 16 MiB
  const size_t WW2 = (size_t)ND * ND * 2;  //  2 MiB
  char* w = (char*)d_ws;
  unsigned short* xb  = (unsigned short*)w; w += MD2;
  unsigned short* Qt  = (unsigned short*)w; w += MD2;   // Qt,Kt contiguous
  unsigned short* Kt  = (unsigned short*)w; w += MD2;
  unsigned short* Vt2 = (unsigned short*)w; w += MD2;
  unsigned short* Wqb = (unsigned short*)w; w += WW2;   // Wq,Wk,Wv contiguous
  unsigned short* Wkb = (unsigned short*)w; w += WW2;
  unsigned short* Wvb = (unsigned short*)w; w += WW2;
  unsigned short* Wob = (unsigned short*)w; w += WW2;
  unsigned short* Ot  = xb;  // alias: xb dead after gemm_qkv_fused

  cast_all<<<dim3(12288), 256, 0, stream>>>(x, Wq, Wk, Wv, Wo, xb, Wqb, Wkb, Wvb, Wob);
  gemm_qkv_fused<<<dim3(16, 64), 512, 0, stream>>>(xb, Wqb, tp, Qt, Vt2);
  attn_kernel<<<dim3(1024), 512, 0, stream>>>(Qt, Kt, Vt2, Ot);
  gemm_out<<<dim3(8, 64), 256, 0, stream>>>(Ot, Wob, out);
}

// Round 17
// 169.375 us; speedup vs baseline: 1.0020x; 1.0020x over previous
//
#include <hip/hip_runtime.h>
#include <stdint.h>

#define NB 4
#define NS 2048
#define ND 1024
#define NH 16
#define NM 8192   // NB*NS

typedef __attribute__((ext_vector_type(4))) float          f32x4;
typedef __attribute__((ext_vector_type(8))) __bf16         bf16x8;
typedef __attribute__((ext_vector_type(8))) unsigned short u16x8;
typedef __attribute__((ext_vector_type(4))) unsigned short u16x4;

static __device__ __forceinline__ unsigned short f2bf(float f) {
  unsigned u = __builtin_bit_cast(unsigned, f);
  return (unsigned short)((u + 0x7fffu + ((u >> 16) & 1u)) >> 16);
}

#if __has_builtin(__builtin_amdgcn_exp2f)
#define EX2(x) __builtin_amdgcn_exp2f(x)
#else
#define EX2(x) __expf((x) * 0.69314718056f)
#endif
#if __has_builtin(__builtin_amdgcn_rcpf)
#define RCP(x) __builtin_amdgcn_rcpf(x)
#else
#define RCP(x) (1.0f / (x))
#endif

static __device__ __forceinline__ unsigned cvtpk(float lo, float hi) {
  unsigned r;
  asm("v_cvt_pk_bf16_f32 %0, %1, %2" : "=v"(r) : "v"(lo), "v"(hi));
  return r;
}

static __device__ __forceinline__ float max3f(float a, float b, float c) {
  return fmaxf(fmaxf(a, b), c);   // clang fuses to v_max3_f32
}

static __device__ __forceinline__ void gld_lds16(const void* g, void* l) {
  __builtin_amdgcn_global_load_lds((const __attribute__((address_space(1))) void*)g,
                                   (__attribute__((address_space(3))) void*)l, 16, 0, 0);
}

// ---------------------------------------------------------------- cast f32->bf16
// single dispatch: blocks [0,8192) = x, [8192,12288) = the four weights
__global__ __launch_bounds__(256) void cast_all(
    const float* __restrict__ x,
    const float* __restrict__ Wq, const float* __restrict__ Wk,
    const float* __restrict__ Wv, const float* __restrict__ Wo,
    unsigned short* __restrict__ xb,
    unsigned short* __restrict__ Wqb, unsigned short* __restrict__ Wkb,
    unsigned short* __restrict__ Wvb, unsigned short* __restrict__ Wob)
{
  const int bx = blockIdx.x;
  const float* in;
  unsigned short* out;
  int i;
  if (bx < 8192) {
    in = x; out = xb; i = bx * 256 + threadIdx.x;
  } else {
    const int z  = (bx - 8192) >> 10;
    const int lb = (bx - 8192) & 1023;
    in  = (z == 0) ? Wq  : (z == 1) ? Wk  : (z == 2) ? Wv  : Wo;
    out = (z == 0) ? Wqb : (z == 1) ? Wkb : (z == 2) ? Wvb : Wob;
    i = lb * 256 + threadIdx.x;
  }
  f32x4 v = ((const f32x4*)in)[i];
  u16x4 o;
#pragma unroll
  for (int e = 0; e < 4; ++e) o[e] = f2bf(v[e]);
  ((u16x4*)out)[i] = o;
}

// ---------------------------------------------------------------- fused QKV GEMM
// 128m x 64n x 3z tile, 2-phase dbuf, 8 waves (512 thr, 4m x 2n): LDS 40KB ->
// 4 WG/CU, all 1024 WGs resident in ONE round.
__global__ __launch_bounds__(512, 4) void gemm_qkv_fused(
    const unsigned short* __restrict__ A,      // xb [8192][1024]
    const unsigned short* __restrict__ Wqkv,   // Wq,Wk,Wv contiguous [1024][1024]
    const int* __restrict__ tp,
    unsigned short* __restrict__ QKt,          // Qt,Kt contiguous [8192][1024]
    unsigned short* __restrict__ Vt2)          // [64 bh][64 d][2048 s]
{
  union SMem {
    struct { unsigned short As[2][128 * 32]; unsigned short Bs[2][3][64 * 32]; } g;
    unsigned short Tt[64][136];  // V-transpose scratch (pad 136)
  };
  __shared__ SMem sm;

  const int tid  = threadIdx.x;              // 0..511
  const int wid  = tid >> 6, lane = tid & 63;
  const int ln   = lane & 15, kg = lane >> 4;
  const int wr   = wid >> 1,  wc = wid & 1;  // 4m x 2n wave grid
  const int m0   = blockIdx.y * 128, n0 = blockIdx.x * 64;

  const int rA = tid >> 2, sA = tid & 3;
  const int fA = (rA & 3) ^ ((rA >> 2) & 3);
  const unsigned short* gA = A + (size_t)(m0 + rA) * ND + ((sA ^ fA) * 8);
  const int dA = tid * 8;

  const int z01 = tid >> 8, cB0 = tid & 255;
  const int rB0 = cB0 >> 2, sB0 = cB0 & 3;
  const int fB0 = (rB0 & 3) ^ ((rB0 >> 2) & 3);
  const unsigned short* gB0 =
      Wqkv + (size_t)z01 * ND * ND + (size_t)(n0 + rB0) * ND + ((sB0 ^ fB0) * 8);
  const int dB0 = cB0 * 8;
  const bool hasB1 = (tid < 256);
  const int rB1 = tid >> 2, sB1 = tid & 3;
  const int fB1 = (rB1 & 3) ^ ((rB1 >> 2) & 3);
  const unsigned short* gB1 =
      Wqkv + (size_t)2 * ND * ND + (size_t)(n0 + rB1) * ND + ((sB1 ^ fB1) * 8);
  const int dB1 = tid * 8;

  const int fql = (ln & 3) ^ ((ln >> 2) & 3);
  const int kco = (kg ^ fql) * 8;
  int offA[2], offB[2];
#pragma unroll
  for (int mi = 0; mi < 2; ++mi)
    offA[mi] = (wr * 32 + mi * 16 + ln) * 32 + kco;
#pragma unroll
  for (int nj = 0; nj < 2; ++nj)
    offB[nj] = (wc * 32 + nj * 16 + ln) * 32 + kco;

  f32x4 acc[3][2][2];
#pragma unroll
  for (int z = 0; z < 3; ++z)
#pragma unroll
    for (int mi = 0; mi < 2; ++mi)
#pragma unroll
      for (int nj = 0; nj < 2; ++nj) acc[z][mi][nj] = (f32x4){0.f, 0.f, 0.f, 0.f};

  gld_lds16(gA,  &sm.g.As[0][dA]);
  gld_lds16(gB0, &sm.g.Bs[0][z01][dB0]);
  if (hasB1) gld_lds16(gB1, &sm.g.Bs[0][2][dB1]);
  gA += 32; gB0 += 32; gB1 += 32;
  __syncthreads();

  for (int t = 0; t < 32; ++t) {
    const int buf = t & 1;
    if (t < 31) {
      const int nb = buf ^ 1;
      gld_lds16(gA,  &sm.g.As[nb][dA]);
      gld_lds16(gB0, &sm.g.Bs[nb][z01][dB0]);
      if (hasB1) gld_lds16(gB1, &sm.g.Bs[nb][2][dB1]);
      gA += 32; gB0 += 32; gB1 += 32;
    }
    bf16x8 af[2];
#pragma unroll
    for (int mi = 0; mi < 2; ++mi) af[mi] = *(const bf16x8*)&sm.g.As[buf][offA[mi]];
#pragma unroll
    for (int z = 0; z < 3; ++z) {
      bf16x8 b0 = *(const bf16x8*)&sm.g.Bs[buf][z][offB[0]];
      bf16x8 b1 = *(const bf16x8*)&sm.g.Bs[buf][z][offB[1]];
#pragma unroll
      for (int mi = 0; mi < 2; ++mi) {
        acc[z][mi][0] = __builtin_amdgcn_mfma_f32_16x16x32_bf16(af[mi], b0, acc[z][mi][0], 0, 0, 0);
        acc[z][mi][1] = __builtin_amdgcn_mfma_f32_16x16x32_bf16(af[mi], b1, acc[z][mi][1], 0, 0, 0);
      }
    }
    __syncthreads();
  }

  // ---- V epilogue: transpose in LDS, write Vt2[bh][d][s] coalesced
#pragma unroll
  for (int mi = 0; mi < 2; ++mi)
#pragma unroll
    for (int r = 0; r < 4; ++r) {
      int ml = wr * 32 + mi * 16 + kg * 4 + r;
#pragma unroll
      for (int nj = 0; nj < 2; ++nj) {
        int nl = wc * 32 + nj * 16 + ln;
        sm.Tt[nl][ml] = f2bf(acc[2][mi][nj][r]);
      }
    }
  __syncthreads();
  {
    const int bq = m0 >> 11, s0 = m0 & 2047;
    unsigned short* vdst = Vt2 + ((size_t)(bq * 16 + blockIdx.x) * 64) * NS + s0;
#pragma unroll
    for (int k = 0; k < 2; ++k) {
      int q = tid + k * 512;
      int row = q >> 4, off = q & 15;
      u16x8 v = *(const u16x8*)&sm.Tt[row][off * 8];
      *(u16x8*)(vdst + (size_t)row * NS + off * 8) = v;
    }
  }

  // ---- Q,K epilogue with fused RoPE (invf/sincos hoisted, shared across z)
  float invf[2];
#pragma unroll
  for (int nj = 0; nj < 2; ++nj) {
    int n  = n0 + wc * 32 + nj * 16 + ln;
    int ip = (n & 63) >> 1;
    invf[nj] = __expf(-0.28782313662425572f * (float)ip);
  }
  const float SC_Q = 0.18033688011111543f;   // 0.125 * log2(e), folded into Q
#pragma unroll
  for (int mi = 0; mi < 2; ++mi)
#pragma unroll
    for (int r = 0; r < 4; ++r) {
      int m = m0 + wr * 32 + mi * 16 + kg * 4 + r;
      float pos = (float)tp[m];
#pragma unroll
      for (int nj = 0; nj < 2; ++nj) {
        int n = n0 + wc * 32 + nj * 16 + ln;
        float sn, cs;
        __sincosf(pos * invf[nj], &sn, &cs);
#pragma unroll
        for (int z = 0; z < 2; ++z) {
          float v  = acc[z][mi][nj][r];
          float pv = __shfl_xor(v, 1);
          float outv = (n & 1) ? (pv * sn + v * cs) : (v * cs - pv * sn);
          if (z == 0) outv *= SC_Q;
          QKt[(size_t)z * NM * ND + (size_t)m * ND + n] = f2bf(outv);
        }
      }
    }
}

// ---------------------------------------------------------------- output GEMM
__global__ __launch_bounds__(256, 4) void gemm_out(
    const unsigned short* __restrict__ A,
    const unsigned short* __restrict__ Bw,
    float* __restrict__ C)
{
  __shared__ unsigned short As[2][128 * 32];
  __shared__ unsigned short Bs[2][128 * 32];

  const int tid  = threadIdx.x;
  const int wid  = tid >> 6, lane = tid & 63;
  const int ln   = lane & 15, kg = lane >> 4;
  const int wr   = wid >> 1,  wc = wid & 1;
  const int m0   = blockIdx.y * 128, n0 = blockIdx.x * 128;

  const int r0 = tid >> 2,        s0 = tid & 3;
  const int r1 = (tid + 256) >> 2;
  const int f0 = (r0 & 3) ^ ((r0 >> 2) & 3);
  const int f1 = (r1 & 3) ^ ((r1 >> 2) & 3);

  const unsigned short* gA0 = A  + (size_t)(m0 + r0) * ND + ((s0 ^ f0) * 8);
  const unsigned short* gA1 = A  + (size_t)(m0 + r1) * ND + ((s0 ^ f1) * 8);
  const unsigned short* gB0 = Bw + (size_t)(n0 + r0) * ND + ((s0 ^ f0) * 8);
  const unsigned short* gB1 = Bw + (size_t)(n0 + r1) * ND + ((s0 ^ f1) * 8);

  const int ldsO0 = wid * 512, ldsO1 = 2048 + wid * 512;

  const int fql = (ln & 3) ^ ((ln >> 2) & 3);
  int offA[4], offB[4];
#pragma unroll
  for (int i = 0; i < 4; ++i) {
    offA[i] = (wr * 64 + i * 16 + ln) * 32 + ((kg ^ fql) * 8);
    offB[i] = (wc * 64 + i * 16 + ln) * 32 + ((kg ^ fql) * 8);
  }

  f32x4 acc[4][4];
#pragma unroll
  for (int i = 0; i < 4; ++i)
#pragma unroll
    for (int j = 0; j < 4; ++j) acc[i][j] = (f32x4){0.f, 0.f, 0.f, 0.f};

  gld_lds16(gA0, &As[0][ldsO0]);
  gld_lds16(gA1, &As[0][ldsO1]);
  gld_lds16(gB0, &Bs[0][ldsO0]);
  gld_lds16(gB1, &Bs[0][ldsO1]);
  gA0 += 32; gA1 += 32; gB0 += 32; gB1 += 32;
  __syncthreads();

  for (int t = 0; t < 32; ++t) {
    const int buf = t & 1;
    if (t < 31) {
      const int nb = buf ^ 1;
      gld_lds16(gA0, &As[nb][ldsO0]);
      gld_lds16(gA1, &As[nb][ldsO1]);
      gld_lds16(gB0, &Bs[nb][ldsO0]);
      gld_lds16(gB1, &Bs[nb][ldsO1]);
      gA0 += 32; gA1 += 32; gB0 += 32; gB1 += 32;
    }
    bf16x8 af[4], bfr[4];
#pragma unroll
    for (int i = 0; i < 4; ++i) af[i] = *(const bf16x8*)&As[buf][offA[i]];
#pragma unroll
    for (int j = 0; j < 4; ++j) bfr[j] = *(const bf16x8*)&Bs[buf][offB[j]];
#pragma unroll
    for (int i = 0; i < 4; ++i)
#pragma unroll
      for (int j = 0; j < 4; ++j)
        acc[i][j] = __builtin_amdgcn_mfma_f32_16x16x32_bf16(af[i], bfr[j], acc[i][j], 0, 0, 0);
    __syncthreads();
  }

#pragma unroll
  for (int i = 0; i < 4; ++i)
#pragma unroll
    for (int j = 0; j < 4; ++j)
#pragma unroll
      for (int r = 0; r < 4; ++r) {
        int m = m0 + wr * 64 + i * 16 + kg * 4 + r;
        int n = n0 + wc * 64 + j * 16 + ln;
        C[(size_t)m * ND + n] = acc[i][j][r];
      }
}

// ---------------------------------------------------------------- flash attention
// 8 waves x 16 q-rows, 1024 WGs XCD-grouped, gld_lds dbuf K/V, row-sum via
// ones-MFMA, max3 tree, defer-max, exp2 domain (Q pre-scaled).
__global__ __launch_bounds__(512, 8) void attn_kernel(
    const unsigned short* __restrict__ Q,
    const unsigned short* __restrict__ K,
    const unsigned short* __restrict__ Vt2,
    unsigned short* __restrict__ O)
{
  __shared__ unsigned short Ks[2][64 * 64];
  __shared__ unsigned short Vs[2][64 * 64];
  __shared__ unsigned long long Pw[8][256];   // per-wave 2KB P/O staging

  const int tid = threadIdx.x;
  const int wid = tid >> 6, lane = tid & 63;
  const int ln  = lane & 15, kg = lane >> 4;

  const int flat = blockIdx.x;
  const int xcd  = flat & 7, g = flat >> 3;   // g in 0..127
  const int qb   = 15 - (g >> 3);             // 128-row q-block, longest first
  const int bh   = xcd + ((g & 7) << 3);      // bh % 8 == xcd
  const int b    = bh >> 4, h = bh & 15;

  const size_t base  = (size_t)b * NS * ND + (size_t)h * 64;
  const size_t vbase = (size_t)bh * 64 * NS;

  const int rA = tid >> 3, slA = tid & 7;
  const unsigned short* KgA = K + base + (size_t)rA * ND + ((slA ^ (rA & 7)) * 8);
  const unsigned short* VgA = Vt2 + vbase + (size_t)rA * NS + ((slA ^ (rA & 7)) * 8);
  const int ldsOff = tid * 8;

  char* pwb = (char*)&Pw[wid][0];
  int wb[4];
#pragma unroll
  for (int j = 0; j < 4; ++j)
    wb[j] = ln * 128 + (((2 * j + (kg >> 1)) ^ (ln & 7)) << 4) + ((kg & 1) << 3);
  const int rb0 = ln * 128 + ((kg ^ (ln & 7)) << 4);
  const int rb1 = ln * 128 + (((4 + kg) ^ (ln & 7)) << 4);

  const int nt   = 2 * qb + 2;
  const int q0   = qb * 128 + wid * 16;
  const int qrow = wid * 16 + ln;

  bf16x8 qf[2];
  {
    const unsigned short* qp = Q + base + (size_t)(q0 + ln) * ND + kg * 8;
    qf[0] = *(const bf16x8*)qp;
    qf[1] = *(const bf16x8*)(qp + 32);
  }

  bf16x8 onesf;
  {
    u16x8 t;
#pragma unroll
    for (int e = 0; e < 8; ++e) t[e] = 0x3F80;   // bf16 1.0
    onesf = __builtin_bit_cast(bf16x8, t);
  }

  float m_run = -1e30f;
  f32x4 acc_o[4];
  f32x4 acc_l = (f32x4){0.f, 0.f, 0.f, 0.f};   // ones-row MFMA: l = acc_l[0]
#pragma unroll
  for (int dj = 0; dj < 4; ++dj) acc_o[dj] = (f32x4){0.f, 0.f, 0.f, 0.f};

  gld_lds16(KgA, &Ks[0][ldsOff]);
  gld_lds16(VgA, &Vs[0][ldsOff]);
  __syncthreads();

  for (int t = 0; t < nt; ++t) {
    const int buf = t & 1;
    if (t + 1 < nt) {
      const size_t ko = (size_t)(t + 1) * 64 * ND;
      const int    vo = (t + 1) * 64;
      const int nb = buf ^ 1;
      gld_lds16(KgA + ko, &Ks[nb][ldsOff]);
      gld_lds16(VgA + vo, &Vs[nb][ldsOff]);
    }

    // ---- S^T = K·Q^T (exp2 domain)
    f32x4 st[4];
    __builtin_amdgcn_s_setprio(1);
#pragma unroll
    for (int j = 0; j < 4; ++j) {
      int kvr = j * 16 + ln;
      bf16x8 k0 = *(const bf16x8*)&Ks[buf][kvr * 64 + ((kg ^ (kvr & 7)) * 8)];
      bf16x8 k1 = *(const bf16x8*)&Ks[buf][kvr * 64 + (((4 + kg) ^ (kvr & 7)) * 8)];
      f32x4 z = (f32x4){0.f, 0.f, 0.f, 0.f};
      z = __builtin_amdgcn_mfma_f32_16x16x32_bf16(k0, qf[0], z, 0, 0, 0);
      z = __builtin_amdgcn_mfma_f32_16x16x32_bf16(k1, qf[1], z, 0, 0, 0);
      st[j] = z;
    }
    __builtin_amdgcn_s_setprio(0);

    const int trel = t - 2 * qb;
    if (trel >= 0) {
#pragma unroll
      for (int j = 0; j < 4; ++j)
#pragma unroll
        for (int r = 0; r < 4; ++r)
          if (trel * 64 + 16 * j + 4 * kg + r > qrow) st[j][r] = -1e30f;
    }

    // ---- row max via v_max3 tree
    float t1 = max3f(st[0][0], st[0][1], st[0][2]);
    float t2 = max3f(st[0][3], st[1][0], st[1][1]);
    float t3 = max3f(st[1][2], st[1][3], st[2][0]);
    float t4 = max3f(st[2][1], st[2][2], st[2][3]);
    float t5 = max3f(st[3][0], st[3][1], st[3][2]);
    float mx = fmaxf(max3f(t1, t2, t3), max3f(t4, t5, st[3][3]));
    mx = fmaxf(mx, __shfl_xor(mx, 16));
    mx = fmaxf(mx, __shfl_xor(mx, 32));

    // ---- defer-max rescale (applies to O and l accumulators)
    if (__any(mx > m_run + 11.0f)) {
      float mnew = fmaxf(m_run, mx);
      float alpha = EX2(m_run - mnew);
      m_run = mnew;
#pragma unroll
      for (int r = 0; r < 4; ++r) acc_l[r] *= alpha;
#pragma unroll
      for (int dj = 0; dj < 4; ++dj)
#pragma unroll
        for (int r = 0; r < 4; ++r) acc_o[dj][r] *= alpha;
    }

#pragma unroll
    for (int j = 0; j < 4; ++j)
#pragma unroll
      for (int r = 0; r < 4; ++r) st[j][r] = EX2(st[j][r] - m_run);

#pragma unroll
    for (int j = 0; j < 4; ++j) {
      unsigned w0 = cvtpk(st[j][0], st[j][1]);
      unsigned w1 = cvtpk(st[j][2], st[j][3]);
      *(unsigned long long*)(pwb + wb[j]) =
          (unsigned long long)w0 | ((unsigned long long)w1 << 32);
    }

    asm volatile("s_waitcnt lgkmcnt(0)" ::: "memory");
    __builtin_amdgcn_sched_barrier(0);

    bf16x8 pb0 = *(const bf16x8*)(pwb + rb0);
    bf16x8 pb1 = *(const bf16x8*)(pwb + rb1);
    __builtin_amdgcn_s_setprio(1);
#pragma unroll
    for (int dj = 0; dj < 4; ++dj) {
      int d = dj * 16 + ln;
      bf16x8 vb0 = *(const bf16x8*)&Vs[buf][d * 64 + ((kg ^ (d & 7)) * 8)];
      bf16x8 vb1 = *(const bf16x8*)&Vs[buf][d * 64 + (((4 + kg) ^ (d & 7)) * 8)];
      acc_o[dj] = __builtin_amdgcn_mfma_f32_16x16x32_bf16(vb0, pb0, acc_o[dj], 0, 0, 0);
      acc_o[dj] = __builtin_amdgcn_mfma_f32_16x16x32_bf16(vb1, pb1, acc_o[dj], 0, 0, 0);
    }
    // row-sum on the matrix pipe: every output row of (ones · P^T) = sum_kv P
    acc_l = __builtin_amdgcn_mfma_f32_16x16x32_bf16(onesf, pb0, acc_l, 0, 0, 0);
    acc_l = __builtin_amdgcn_mfma_f32_16x16x32_bf16(onesf, pb1, acc_l, 0, 0, 0);
    __builtin_amdgcn_s_setprio(0);
    __syncthreads();
  }

  asm volatile("s_waitcnt lgkmcnt(0)" ::: "memory");
  float inv = RCP(acc_l[0]);
#pragma unroll
  for (int dj = 0; dj < 4; ++dj) {
    unsigned w0 = cvtpk(acc_o[dj][0] * inv, acc_o[dj][1] * inv);
    unsigned w1 = cvtpk(acc_o[dj][2] * inv, acc_o[dj][3] * inv);
    *(unsigned long long*)(pwb + wb[dj]) =
        (unsigned long long)w0 | ((unsigned long long)w1 << 32);
  }
  asm volatile("s_waitcnt lgkmcnt(0)" ::: "memory");
  __builtin_amdgcn_sched_barrier(0);
  {
    const int orow = lane >> 3, og = lane & 7;
    const int lb = ((og ^ (orow & 7)) << 4);
    u16x8 o0 = *(const u16x8*)(pwb + orow * 128 + lb);
    u16x8 o1 = *(const u16x8*)(pwb + (8 + orow) * 128 + lb);
    *(u16x8*)(O + base + (size_t)(q0 + orow) * ND + og * 8) = o0;
    *(u16x8*)(O + base + (size_t)(q0 + 8 + orow) * ND + og * 8) = o1;
  }
}

// ---------------------------------------------------------------- launcher
extern "C" void kernel_launch(void* const* d_in, const int* in_sizes, int n_in,
                              void* d_out, int out_size, void* d_ws, size_t ws_size,
                              hipStream_t stream) {
  const float* x  = (const float*)d_in[0];
  const int*   tp = (const int*)d_in[1];
  const float* Wq = (const float*)d_in[2];
  const float* Wk = (const float*)d_in[3];
  const float* Wv = (const float*)d_in[4];
  const float* Wo = (const float*)d_in[5];
  float* out = (float*)d_out;

  const size_t MD2 = (size_t)NM * ND * 2;  // 16 MiB
  const size_t WW2 = (size_t)ND * ND * 2;  //  2 MiB
  char* w = (char*)d_ws;
  unsigned short* xb  = (unsigned short*)w; w += MD2;
  unsigned short* Qt  = (unsigned short*)w; w += MD2;   // Qt,Kt contiguous
  unsigned short* Kt  = (unsigned short*)w; w += MD2;
  unsigned short* Vt2 = (unsigned short*)w; w += MD2;
  unsigned short* Wqb = (unsigned short*)w; w += WW2;   // Wq,Wk,Wv contiguous
  unsigned short* Wkb = (unsigned short*)w; w += WW2;
  unsigned short* Wvb = (unsigned short*)w; w += WW2;
  unsigned short* Wob = (unsigned short*)w; w += WW2;
  unsigned short* Ot  = xb;  // alias: xb dead after gemm_qkv_fused

  cast_all<<<dim3(12288), 256, 0, stream>>>(x, Wq, Wk, Wv, Wo, xb, Wqb, Wkb, Wvb, Wob);
  gemm_qkv_fused<<<dim3(16, 64), 512, 0, stream>>>(xb, Wqb, tp, Qt, Vt2);
  attn_kernel<<<dim3(1024), 512, 0, stream>>>(Qt, Kt, Vt2, Ot);
  gemm_out<<<dim3(8, 64), 256, 0, stream>>>(Ot, Wob, out);
}

// Round 18
// 167.335 us; speedup vs baseline: 1.0142x; 1.0122x over previous
//
#include <hip/hip_runtime.h>
#include <stdint.h>

#define NB 4
#define NS 2048
#define ND 1024
#define NH 16
#define NM 8192   // NB*NS

typedef __attribute__((ext_vector_type(4))) float          f32x4;
typedef __attribute__((ext_vector_type(8))) __bf16         bf16x8;
typedef __attribute__((ext_vector_type(8))) unsigned short u16x8;
typedef __attribute__((ext_vector_type(4))) unsigned short u16x4;

static __device__ __forceinline__ unsigned short f2bf(float f) {
  unsigned u = __builtin_bit_cast(unsigned, f);
  return (unsigned short)((u + 0x7fffu + ((u >> 16) & 1u)) >> 16);
}

#if __has_builtin(__builtin_amdgcn_exp2f)
#define EX2(x) __builtin_amdgcn_exp2f(x)
#else
#define EX2(x) __expf((x) * 0.69314718056f)
#endif
#if __has_builtin(__builtin_amdgcn_rcpf)
#define RCP(x) __builtin_amdgcn_rcpf(x)
#else
#define RCP(x) (1.0f / (x))
#endif

static __device__ __forceinline__ unsigned cvtpk(float lo, float hi) {
  unsigned r;
  asm("v_cvt_pk_bf16_f32 %0, %1, %2" : "=v"(r) : "v"(lo), "v"(hi));
  return r;
}

static __device__ __forceinline__ float max3f(float a, float b, float c) {
  return fmaxf(fmaxf(a, b), c);   // clang fuses to v_max3_f32
}

static __device__ __forceinline__ void gld_lds16(const void* g, void* l) {
  __builtin_amdgcn_global_load_lds((const __attribute__((address_space(1))) void*)g,
                                   (__attribute__((address_space(3))) void*)l, 16, 0, 0);
}

// ---------------------------------------------------------------- cast f32->bf16
// single dispatch: blocks [0,8192) = x, [8192,12288) = the four weights
__global__ __launch_bounds__(256) void cast_all(
    const float* __restrict__ x,
    const float* __restrict__ Wq, const float* __restrict__ Wk,
    const float* __restrict__ Wv, const float* __restrict__ Wo,
    unsigned short* __restrict__ xb,
    unsigned short* __restrict__ Wqb, unsigned short* __restrict__ Wkb,
    unsigned short* __restrict__ Wvb, unsigned short* __restrict__ Wob)
{
  const int bx = blockIdx.x;
  const float* in;
  unsigned short* out;
  int i;
  if (bx < 8192) {
    in = x; out = xb; i = bx * 256 + threadIdx.x;
  } else {
    const int z  = (bx - 8192) >> 10;
    const int lb = (bx - 8192) & 1023;
    in  = (z == 0) ? Wq  : (z == 1) ? Wk  : (z == 2) ? Wv  : Wo;
    out = (z == 0) ? Wqb : (z == 1) ? Wkb : (z == 2) ? Wvb : Wob;
    i = lb * 256 + threadIdx.x;
  }
  f32x4 v = ((const f32x4*)in)[i];
  u16x4 o;
#pragma unroll
  for (int e = 0; e < 4; ++e) o[e] = f2bf(v[e]);
  ((u16x4*)out)[i] = o;
}

// ---------------------------------------------------------------- fused QKV GEMM
// (config A: 128m x 64n x 3z, 2-phase dbuf, 4 waves, min-waves 3)
__global__ __launch_bounds__(256, 3) void gemm_qkv_fused(
    const unsigned short* __restrict__ A,      // xb [8192][1024]
    const unsigned short* __restrict__ Wqkv,   // Wq,Wk,Wv contiguous [1024][1024]
    const int* __restrict__ tp,
    unsigned short* __restrict__ QKt,          // Qt,Kt contiguous [8192][1024]
    unsigned short* __restrict__ Vt2)          // [64 bh][64 d][2048 s]
{
  union SMem {
    struct { unsigned short As[2][128 * 32]; unsigned short Bs[2][3][64 * 32]; } g;
    unsigned short Tt[64][136];  // V-transpose scratch (pad 136: 2-way banks)
  };
  __shared__ SMem sm;

  const int tid  = threadIdx.x;
  const int wid  = tid >> 6, lane = tid & 63;
  const int ln   = lane & 15, kg = lane >> 4;
  const int wr   = wid >> 1,  wc = wid & 1;
  const int m0   = blockIdx.y * 128, n0 = blockIdx.x * 64;

  const int rA0 = tid >> 2,        sA = tid & 3;
  const int rA1 = (tid + 256) >> 2;
  const int fA0 = (rA0 & 3) ^ ((rA0 >> 2) & 3);
  const int fA1 = (rA1 & 3) ^ ((rA1 >> 2) & 3);
  const int rB = tid >> 2;
  const int fB = (rB & 3) ^ ((rB >> 2) & 3);

  const unsigned short* gA0 = A + (size_t)(m0 + rA0) * ND + ((sA ^ fA0) * 8);
  const unsigned short* gA1 = A + (size_t)(m0 + rA1) * ND + ((sA ^ fA1) * 8);
  const unsigned short* gBq = Wqkv + (size_t)(n0 + rB) * ND + ((sA ^ fB) * 8);
  const unsigned short* gBk = gBq + (size_t)ND * ND;
  const unsigned short* gBv = gBk + (size_t)ND * ND;

  const int ldsA0 = wid * 512;
  const int ldsA1 = 2048 + wid * 512;
  const int ldsB  = wid * 512;

  const int fql = (ln & 3) ^ ((ln >> 2) & 3);
  int offA[4], offB[2];
#pragma unroll
  for (int i = 0; i < 4; ++i)
    offA[i] = (wr * 64 + i * 16 + ln) * 32 + ((kg ^ fql) * 8);
#pragma unroll
  for (int j = 0; j < 2; ++j)
    offB[j] = (wc * 32 + j * 16 + ln) * 32 + ((kg ^ fql) * 8);

  f32x4 acc[3][4][2];
#pragma unroll
  for (int z = 0; z < 3; ++z)
#pragma unroll
    for (int i = 0; i < 4; ++i)
#pragma unroll
      for (int j = 0; j < 2; ++j) acc[z][i][j] = (f32x4){0.f, 0.f, 0.f, 0.f};

  gld_lds16(gA0, &sm.g.As[0][ldsA0]);
  gld_lds16(gA1, &sm.g.As[0][ldsA1]);
  gld_lds16(gBq, &sm.g.Bs[0][0][ldsB]);
  gld_lds16(gBk, &sm.g.Bs[0][1][ldsB]);
  gld_lds16(gBv, &sm.g.Bs[0][2][ldsB]);
  gA0 += 32; gA1 += 32; gBq += 32; gBk += 32; gBv += 32;
  __syncthreads();

  for (int t = 0; t < 32; ++t) {
    const int buf = t & 1;
    if (t < 31) {
      const int nb = buf ^ 1;
      gld_lds16(gA0, &sm.g.As[nb][ldsA0]);
      gld_lds16(gA1, &sm.g.As[nb][ldsA1]);
      gld_lds16(gBq, &sm.g.Bs[nb][0][ldsB]);
      gld_lds16(gBk, &sm.g.Bs[nb][1][ldsB]);
      gld_lds16(gBv, &sm.g.Bs[nb][2][ldsB]);
      gA0 += 32; gA1 += 32; gBq += 32; gBk += 32; gBv += 32;
    }
    bf16x8 af[4];
#pragma unroll
    for (int i = 0; i < 4; ++i) af[i] = *(const bf16x8*)&sm.g.As[buf][offA[i]];
#pragma unroll
    for (int z = 0; z < 3; ++z) {
      bf16x8 b0 = *(const bf16x8*)&sm.g.Bs[buf][z][offB[0]];
      bf16x8 b1 = *(const bf16x8*)&sm.g.Bs[buf][z][offB[1]];
#pragma unroll
      for (int i = 0; i < 4; ++i) {
        acc[z][i][0] = __builtin_amdgcn_mfma_f32_16x16x32_bf16(af[i], b0, acc[z][i][0], 0, 0, 0);
        acc[z][i][1] = __builtin_amdgcn_mfma_f32_16x16x32_bf16(af[i], b1, acc[z][i][1], 0, 0, 0);
      }
    }
    __syncthreads();
  }

  // ---- V epilogue: transpose in LDS, write Vt2[bh][d][s] coalesced
#pragma unroll
  for (int i = 0; i < 4; ++i)
#pragma unroll
    for (int r = 0; r < 4; ++r) {
      int ml = wr * 64 + i * 16 + kg * 4 + r;
#pragma unroll
      for (int j = 0; j < 2; ++j) {
        int nl = wc * 32 + j * 16 + ln;
        sm.Tt[nl][ml] = f2bf(acc[2][i][j][r]);
      }
    }
  __syncthreads();
  {
    const int b = m0 >> 11, s0 = m0 & 2047;
    unsigned short* vdst = Vt2 + ((size_t)(b * 16 + blockIdx.x) * 64) * NS + s0;
#pragma unroll
    for (int k = 0; k < 4; ++k) {
      int q = tid + k * 256;
      int row = q >> 4, off = q & 15;
      u16x8 v = *(const u16x8*)&sm.Tt[row][off * 8];
      *(u16x8*)(vdst + (size_t)row * NS + off * 8) = v;
    }
  }

  // ---- Q,K epilogue with fused RoPE (invf/sincos hoisted, shared across z)
  float invf[2];
#pragma unroll
  for (int j = 0; j < 2; ++j) {
    int n  = n0 + wc * 32 + j * 16 + ln;
    int ip = (n & 63) >> 1;
    invf[j] = __expf(-0.28782313662425572f * (float)ip);
  }
  const float SC_Q = 0.18033688011111543f;   // 0.125 * log2(e), folded into Q
#pragma unroll
  for (int i = 0; i < 4; ++i)
#pragma unroll
    for (int r = 0; r < 4; ++r) {
      int m = m0 + wr * 64 + i * 16 + kg * 4 + r;
      float pos = (float)tp[m];
#pragma unroll
      for (int j = 0; j < 2; ++j) {
        int n = n0 + wc * 32 + j * 16 + ln;
        float sn, cs;
        __sincosf(pos * invf[j], &sn, &cs);
#pragma unroll
        for (int z = 0; z < 2; ++z) {
          float v  = acc[z][i][j][r];
          float pv = __shfl_xor(v, 1);
          float outv = (n & 1) ? (pv * sn + v * cs) : (v * cs - pv * sn);
          if (z == 0) outv *= SC_Q;
          QKt[(size_t)z * NM * ND + (size_t)m * ND + n] = f2bf(outv);
        }
      }
    }
}

// ---------------------------------------------------------------- output GEMM
__global__ __launch_bounds__(256, 4) void gemm_out(
    const unsigned short* __restrict__ A,
    const unsigned short* __restrict__ Bw,
    float* __restrict__ C)
{
  __shared__ unsigned short As[2][128 * 32];
  __shared__ unsigned short Bs[2][128 * 32];

  const int tid  = threadIdx.x;
  const int wid  = tid >> 6, lane = tid & 63;
  const int ln   = lane & 15, kg = lane >> 4;
  const int wr   = wid >> 1,  wc = wid & 1;
  const int m0   = blockIdx.y * 128, n0 = blockIdx.x * 128;

  const int r0 = tid >> 2,        s0 = tid & 3;
  const int r1 = (tid + 256) >> 2;
  const int f0 = (r0 & 3) ^ ((r0 >> 2) & 3);
  const int f1 = (r1 & 3) ^ ((r1 >> 2) & 3);

  const unsigned short* gA0 = A  + (size_t)(m0 + r0) * ND + ((s0 ^ f0) * 8);
  const unsigned short* gA1 = A  + (size_t)(m0 + r1) * ND + ((s0 ^ f1) * 8);
  const unsigned short* gB0 = Bw + (size_t)(n0 + r0) * ND + ((s0 ^ f0) * 8);
  const unsigned short* gB1 = Bw + (size_t)(n0 + r1) * ND + ((s0 ^ f1) * 8);

  const int ldsO0 = wid * 512, ldsO1 = 2048 + wid * 512;

  const int fql = (ln & 3) ^ ((ln >> 2) & 3);
  int offA[4], offB[4];
#pragma unroll
  for (int i = 0; i < 4; ++i) {
    offA[i] = (wr * 64 + i * 16 + ln) * 32 + ((kg ^ fql) * 8);
    offB[i] = (wc * 64 + i * 16 + ln) * 32 + ((kg ^ fql) * 8);
  }

  f32x4 acc[4][4];
#pragma unroll
  for (int i = 0; i < 4; ++i)
#pragma unroll
    for (int j = 0; j < 4; ++j) acc[i][j] = (f32x4){0.f, 0.f, 0.f, 0.f};

  gld_lds16(gA0, &As[0][ldsO0]);
  gld_lds16(gA1, &As[0][ldsO1]);
  gld_lds16(gB0, &Bs[0][ldsO0]);
  gld_lds16(gB1, &Bs[0][ldsO1]);
  gA0 += 32; gA1 += 32; gB0 += 32; gB1 += 32;
  __syncthreads();

  for (int t = 0; t < 32; ++t) {
    const int buf = t & 1;
    if (t < 31) {
      const int nb = buf ^ 1;
      gld_lds16(gA0, &As[nb][ldsO0]);
      gld_lds16(gA1, &As[nb][ldsO1]);
      gld_lds16(gB0, &Bs[nb][ldsO0]);
      gld_lds16(gB1, &Bs[nb][ldsO1]);
      gA0 += 32; gA1 += 32; gB0 += 32; gB1 += 32;
    }
    bf16x8 af[4], bfr[4];
#pragma unroll
    for (int i = 0; i < 4; ++i) af[i] = *(const bf16x8*)&As[buf][offA[i]];
#pragma unroll
    for (int j = 0; j < 4; ++j) bfr[j] = *(const bf16x8*)&Bs[buf][offB[j]];
#pragma unroll
    for (int i = 0; i < 4; ++i)
#pragma unroll
      for (int j = 0; j < 4; ++j)
        acc[i][j] = __builtin_amdgcn_mfma_f32_16x16x32_bf16(af[i], bfr[j], acc[i][j], 0, 0, 0);
    __syncthreads();
  }

#pragma unroll
  for (int i = 0; i < 4; ++i)
#pragma unroll
    for (int j = 0; j < 4; ++j)
#pragma unroll
      for (int r = 0; r < 4; ++r) {
        int m = m0 + wr * 64 + i * 16 + kg * 4 + r;
        int n = n0 + wc * 64 + j * 16 + ln;
        C[(size_t)m * ND + n] = acc[i][j][r];
      }
}

// ---------------------------------------------------------------- flash attention
// 8 waves x 16 q-rows, 1024 WGs XCD-grouped, gld_lds dbuf K/V, row-sum via
// ones-MFMA, max3 tree, defer-max, exp2 domain (Q pre-scaled).
__global__ __launch_bounds__(512, 8) void attn_kernel(
    const unsigned short* __restrict__ Q,
    const unsigned short* __restrict__ K,
    const unsigned short* __restrict__ Vt2,
    unsigned short* __restrict__ O)
{
  __shared__ unsigned short Ks[2][64 * 64];
  __shared__ unsigned short Vs[2][64 * 64];
  __shared__ unsigned long long Pw[8][256];   // per-wave 2KB P/O staging

  const int tid = threadIdx.x;
  const int wid = tid >> 6, lane = tid & 63;
  const int ln  = lane & 15, kg = lane >> 4;

  const int flat = blockIdx.x;
  const int xcd  = flat & 7, g = flat >> 3;   // g in 0..127
  const int qb   = 15 - (g >> 3);             // 128-row q-block, longest first
  const int bh   = xcd + ((g & 7) << 3);      // bh % 8 == xcd
  const int b    = bh >> 4, h = bh & 15;

  const size_t base  = (size_t)b * NS * ND + (size_t)h * 64;
  const size_t vbase = (size_t)bh * 64 * NS;

  const int rA = tid >> 3, slA = tid & 7;
  const unsigned short* KgA = K + base + (size_t)rA * ND + ((slA ^ (rA & 7)) * 8);
  const unsigned short* VgA = Vt2 + vbase + (size_t)rA * NS + ((slA ^ (rA & 7)) * 8);
  const int ldsOff = tid * 8;

  char* pwb = (char*)&Pw[wid][0];
  int wb[4];
#pragma unroll
  for (int j = 0; j < 4; ++j)
    wb[j] = ln * 128 + (((2 * j + (kg >> 1)) ^ (ln & 7)) << 4) + ((kg & 1) << 3);
  const int rb0 = ln * 128 + ((kg ^ (ln & 7)) << 4);
  const int rb1 = ln * 128 + (((4 + kg) ^ (ln & 7)) << 4);

  const int nt   = 2 * qb + 2;
  const int q0   = qb * 128 + wid * 16;
  const int qrow = wid * 16 + ln;

  bf16x8 qf[2];
  {
    const unsigned short* qp = Q + base + (size_t)(q0 + ln) * ND + kg * 8;
    qf[0] = *(const bf16x8*)qp;
    qf[1] = *(const bf16x8*)(qp + 32);
  }

  bf16x8 onesf;
  {
    u16x8 t;
#pragma unroll
    for (int e = 0; e < 8; ++e) t[e] = 0x3F80;   // bf16 1.0
    onesf = __builtin_bit_cast(bf16x8, t);
  }

  float m_run = -1e30f;
  f32x4 acc_o[4];
  f32x4 acc_l = (f32x4){0.f, 0.f, 0.f, 0.f};   // ones-row MFMA: l = acc_l[0]
#pragma unroll
  for (int dj = 0; dj < 4; ++dj) acc_o[dj] = (f32x4){0.f, 0.f, 0.f, 0.f};

  gld_lds16(KgA, &Ks[0][ldsOff]);
  gld_lds16(VgA, &Vs[0][ldsOff]);
  __syncthreads();

  for (int t = 0; t < nt; ++t) {
    const int buf = t & 1;
    if (t + 1 < nt) {
      const size_t ko = (size_t)(t + 1) * 64 * ND;
      const int    vo = (t + 1) * 64;
      const int nb = buf ^ 1;
      gld_lds16(KgA + ko, &Ks[nb][ldsOff]);
      gld_lds16(VgA + vo, &Vs[nb][ldsOff]);
    }

    // ---- S^T = K·Q^T (exp2 domain)
    f32x4 st[4];
    __builtin_amdgcn_s_setprio(1);
#pragma unroll
    for (int j = 0; j < 4; ++j) {
      int kvr = j * 16 + ln;
      bf16x8 k0 = *(const bf16x8*)&Ks[buf][kvr * 64 + ((kg ^ (kvr & 7)) * 8)];
      bf16x8 k1 = *(const bf16x8*)&Ks[buf][kvr * 64 + (((4 + kg) ^ (kvr & 7)) * 8)];
      f32x4 z = (f32x4){0.f, 0.f, 0.f, 0.f};
      z = __builtin_amdgcn_mfma_f32_16x16x32_bf16(k0, qf[0], z, 0, 0, 0);
      z = __builtin_amdgcn_mfma_f32_16x16x32_bf16(k1, qf[1], z, 0, 0, 0);
      st[j] = z;
    }
    __builtin_amdgcn_s_setprio(0);

    const int trel = t - 2 * qb;
    if (trel >= 0) {
#pragma unroll
      for (int j = 0; j < 4; ++j)
#pragma unroll
        for (int r = 0; r < 4; ++r)
          if (trel * 64 + 16 * j + 4 * kg + r > qrow) st[j][r] = -1e30f;
    }

    // ---- row max via v_max3 tree
    float t1 = max3f(st[0][0], st[0][1], st[0][2]);
    float t2 = max3f(st[0][3], st[1][0], st[1][1]);
    float t3 = max3f(st[1][2], st[1][3], st[2][0]);
    float t4 = max3f(st[2][1], st[2][2], st[2][3]);
    float t5 = max3f(st[3][0], st[3][1], st[3][2]);
    float mx = fmaxf(max3f(t1, t2, t3), max3f(t4, t5, st[3][3]));
    mx = fmaxf(mx, __shfl_xor(mx, 16));
    mx = fmaxf(mx, __shfl_xor(mx, 32));

    // ---- defer-max rescale (applies to O and l accumulators)
    if (__any(mx > m_run + 11.0f)) {
      float mnew = fmaxf(m_run, mx);
      float alpha = EX2(m_run - mnew);
      m_run = mnew;
#pragma unroll
      for (int r = 0; r < 4; ++r) acc_l[r] *= alpha;
#pragma unroll
      for (int dj = 0; dj < 4; ++dj)
#pragma unroll
        for (int r = 0; r < 4; ++r) acc_o[dj][r] *= alpha;
    }

#pragma unroll
    for (int j = 0; j < 4; ++j)
#pragma unroll
      for (int r = 0; r < 4; ++r) st[j][r] = EX2(st[j][r] - m_run);

#pragma unroll
    for (int j = 0; j < 4; ++j) {
      unsigned w0 = cvtpk(st[j][0], st[j][1]);
      unsigned w1 = cvtpk(st[j][2], st[j][3]);
      *(unsigned long long*)(pwb + wb[j]) =
          (unsigned long long)w0 | ((unsigned long long)w1 << 32);
    }

    asm volatile("s_waitcnt lgkmcnt(0)" ::: "memory");
    __builtin_amdgcn_sched_barrier(0);

    bf16x8 pb0 = *(const bf16x8*)(pwb + rb0);
    bf16x8 pb1 = *(const bf16x8*)(pwb + rb1);
    __builtin_amdgcn_s_setprio(1);
#pragma unroll
    for (int dj = 0; dj < 4; ++dj) {
      int d = dj * 16 + ln;
      bf16x8 vb0 = *(const bf16x8*)&Vs[buf][d * 64 + ((kg ^ (d & 7)) * 8)];
      bf16x8 vb1 = *(const bf16x8*)&Vs[buf][d * 64 + (((4 + kg) ^ (d & 7)) * 8)];
      acc_o[dj] = __builtin_amdgcn_mfma_f32_16x16x32_bf16(vb0, pb0, acc_o[dj], 0, 0, 0);
      acc_o[dj] = __builtin_amdgcn_mfma_f32_16x16x32_bf16(vb1, pb1, acc_o[dj], 0, 0, 0);
    }
    // row-sum on the matrix pipe: every output row of (ones · P^T) = sum_kv P
    acc_l = __builtin_amdgcn_mfma_f32_16x16x32_bf16(onesf, pb0, acc_l, 0, 0, 0);
    acc_l = __builtin_amdgcn_mfma_f32_16x16x32_bf16(onesf, pb1, acc_l, 0, 0, 0);
    __builtin_amdgcn_s_setprio(0);
    __syncthreads();
  }

  asm volatile("s_waitcnt lgkmcnt(0)" ::: "memory");
  float inv = RCP(acc_l[0]);
#pragma unroll
  for (int dj = 0; dj < 4; ++dj) {
    unsigned w0 = cvtpk(acc_o[dj][0] * inv, acc_o[dj][1] * inv);
    unsigned w1 = cvtpk(acc_o[dj][2] * inv, acc_o[dj][3] * inv);
    *(unsigned long long*)(pwb + wb[dj]) =
        (unsigned long long)w0 | ((unsigned long long)w1 << 32);
  }
  asm volatile("s_waitcnt lgkmcnt(0)" ::: "memory");
  __builtin_amdgcn_sched_barrier(0);
  {
    const int orow = lane >> 3, og = lane & 7;
    const int lb = ((og ^ (orow & 7)) << 4);
    u16x8 o0 = *(const u16x8*)(pwb + orow * 128 + lb);
    u16x8 o1 = *(const u16x8*)(pwb + (8 + orow) * 128 + lb);
    *(u16x8*)(O + base + (size_t)(q0 + orow) * ND + og * 8) = o0;
    *(u16x8*)(O + base + (size_t)(q0 + 8 + orow) * ND + og * 8) = o1;
  }
}

// ---------------------------------------------------------------- launcher
extern "C" void kernel_launch(void* const* d_in, const int* in_sizes, int n_in,
                              void* d_out, int out_size, void* d_ws, size_t ws_size,
                              hipStream_t stream) {
  const float* x  = (const float*)d_in[0];
  const int*   tp = (const int*)d_in[1];
  const float* Wq = (const float*)d_in[2];
  const float* Wk = (const float*)d_in[3];
  const float* Wv = (const float*)d_in[4];
  const float* Wo = (const float*)d_in[5];
  float* out = (float*)d_out;

  const size_t MD2 = (size_t)NM * ND * 2;  // 16 MiB
  const size_t WW2 = (size_t)ND * ND * 2;  //  2 MiB
  char* w = (char*)d_ws;
  unsigned short* xb  = (unsigned short*)w; w += MD2;
  unsigned short* Qt  = (unsigned short*)w; w += MD2;   // Qt,Kt contiguous
  unsigned short* Kt  = (unsigned short*)w; w += MD2;
  unsigned short* Vt2 = (unsigned short*)w; w += MD2;
  unsigned short* Wqb = (unsigned short*)w; w += WW2;   // Wq,Wk,Wv contiguous
  unsigned short* Wkb = (unsigned short*)w; w += WW2;
  unsigned short* Wvb = (unsigned short*)w; w += WW2;
  unsigned short* Wob = (unsigned short*)w; w += WW2;
  unsigned short* Ot  = xb;  // alias: xb dead after gemm_qkv_fused

  cast_all<<<dim3(12288), 256, 0, stream>>>(x, Wq, Wk, Wv, Wo, xb, Wqb, Wkb, Wvb, Wob);
  gemm_qkv_fused<<<dim3(16, 64), 256, 0, stream>>>(xb, Wqb, tp, Qt, Vt2);
  attn_kernel<<<dim3(1024), 512, 0, stream>>>(Qt, Kt, Vt2, Ot);
  gemm_out<<<dim3(8, 64), 256, 0, stream>>>(Ot, Wob, out);
}

// Round 20
// 166.553 us; speedup vs baseline: 1.0189x; 1.0047x over previous
//
#include <hip/hip_runtime.h>
#include <stdint.h>

#define NB 4
#define NS 2048
#define ND 1024
#define NH 16
#define NM 8192   // NB*NS

typedef __attribute__((ext_vector_type(4))) float          f32x4;
typedef __attribute__((ext_vector_type(8))) __bf16         bf16x8;
typedef __attribute__((ext_vector_type(8))) unsigned short u16x8;
typedef __attribute__((ext_vector_type(4))) unsigned short u16x4;

static __device__ __forceinline__ unsigned short f2bf(float f) {
  unsigned u = __builtin_bit_cast(unsigned, f);
  return (unsigned short)((u + 0x7fffu + ((u >> 16) & 1u)) >> 16);
}

#if __has_builtin(__builtin_amdgcn_exp2f)
#define EX2(x) __builtin_amdgcn_exp2f(x)
#else
#define EX2(x) __expf((x) * 0.69314718056f)
#endif
#if __has_builtin(__builtin_amdgcn_rcpf)
#define RCP(x) __builtin_amdgcn_rcpf(x)
#else
#define RCP(x) (1.0f / (x))
#endif

static __device__ __forceinline__ unsigned cvtpk(float lo, float hi) {
  unsigned r;
  asm("v_cvt_pk_bf16_f32 %0, %1, %2" : "=v"(r) : "v"(lo), "v"(hi));
  return r;
}

static __device__ __forceinline__ float max3f(float a, float b, float c) {
  return fmaxf(fmaxf(a, b), c);   // clang fuses to v_max3_f32
}

static __device__ __forceinline__ void gld_lds16(const void* g, void* l) {
  __builtin_amdgcn_global_load_lds((const __attribute__((address_space(1))) void*)g,
                                   (__attribute__((address_space(3))) void*)l, 16, 0, 0);
}

// ---------------------------------------------------------------- cast f32->bf16
// single dispatch: blocks [0,8192) = x, [8192,12288) = the four weights
__global__ __launch_bounds__(256) void cast_all(
    const float* __restrict__ x,
    const float* __restrict__ Wq, const float* __restrict__ Wk,
    const float* __restrict__ Wv, const float* __restrict__ Wo,
    unsigned short* __restrict__ xb,
    unsigned short* __restrict__ Wqb, unsigned short* __restrict__ Wkb,
    unsigned short* __restrict__ Wvb, unsigned short* __restrict__ Wob)
{
  const int bx = blockIdx.x;
  const float* in;
  unsigned short* out;
  int i;
  if (bx < 8192) {
    in = x; out = xb; i = bx * 256 + threadIdx.x;
  } else {
    const int z  = (bx - 8192) >> 10;
    const int lb = (bx - 8192) & 1023;
    in  = (z == 0) ? Wq  : (z == 1) ? Wk  : (z == 2) ? Wv  : Wo;
    out = (z == 0) ? Wqb : (z == 1) ? Wkb : (z == 2) ? Wvb : Wob;
    i = lb * 256 + threadIdx.x;
  }
  f32x4 v = ((const f32x4*)in)[i];
  u16x4 o;
#pragma unroll
  for (int e = 0; e < 4; ++e) o[e] = f2bf(v[e]);
  ((u16x4*)out)[i] = o;
}

// ---------------------------------------------------------------- fused QKV GEMM
// (config A: 128m x 64n x 3z, 2-phase dbuf, 4 waves, min-waves 3)
__global__ __launch_bounds__(256, 3) void gemm_qkv_fused(
    const unsigned short* __restrict__ A,      // xb [8192][1024]
    const unsigned short* __restrict__ Wqkv,   // Wq,Wk,Wv contiguous [1024][1024]
    const int* __restrict__ tp,
    unsigned short* __restrict__ QKt,          // Qt,Kt contiguous [8192][1024]
    unsigned short* __restrict__ Vt2)          // [64 bh][64 d][2048 s]
{
  union SMem {
    struct { unsigned short As[2][128 * 32]; unsigned short Bs[2][3][64 * 32]; } g;
    unsigned short Tt[64][136];  // V-transpose scratch (pad 136: 2-way banks)
  };
  __shared__ SMem sm;

  const int tid  = threadIdx.x;
  const int wid  = tid >> 6, lane = tid & 63;
  const int ln   = lane & 15, kg = lane >> 4;
  const int wr   = wid >> 1,  wc = wid & 1;
  const int m0   = blockIdx.y * 128, n0 = blockIdx.x * 64;

  const int rA0 = tid >> 2,        sA = tid & 3;
  const int rA1 = (tid + 256) >> 2;
  const int fA0 = (rA0 & 3) ^ ((rA0 >> 2) & 3);
  const int fA1 = (rA1 & 3) ^ ((rA1 >> 2) & 3);
  const int rB = tid >> 2;
  const int fB = (rB & 3) ^ ((rB >> 2) & 3);

  const unsigned short* gA0 = A + (size_t)(m0 + rA0) * ND + ((sA ^ fA0) * 8);
  const unsigned short* gA1 = A + (size_t)(m0 + rA1) * ND + ((sA ^ fA1) * 8);
  const unsigned short* gBq = Wqkv + (size_t)(n0 + rB) * ND + ((sA ^ fB) * 8);
  const unsigned short* gBk = gBq + (size_t)ND * ND;
  const unsigned short* gBv = gBk + (size_t)ND * ND;

  const int ldsA0 = wid * 512;
  const int ldsA1 = 2048 + wid * 512;
  const int ldsB  = wid * 512;

  const int fql = (ln & 3) ^ ((ln >> 2) & 3);
  int offA[4], offB[2];
#pragma unroll
  for (int i = 0; i < 4; ++i)
    offA[i] = (wr * 64 + i * 16 + ln) * 32 + ((kg ^ fql) * 8);
#pragma unroll
  for (int j = 0; j < 2; ++j)
    offB[j] = (wc * 32 + j * 16 + ln) * 32 + ((kg ^ fql) * 8);

  f32x4 acc[3][4][2];
#pragma unroll
  for (int z = 0; z < 3; ++z)
#pragma unroll
    for (int i = 0; i < 4; ++i)
#pragma unroll
      for (int j = 0; j < 2; ++j) acc[z][i][j] = (f32x4){0.f, 0.f, 0.f, 0.f};

  gld_lds16(gA0, &sm.g.As[0][ldsA0]);
  gld_lds16(gA1, &sm.g.As[0][ldsA1]);
  gld_lds16(gBq, &sm.g.Bs[0][0][ldsB]);
  gld_lds16(gBk, &sm.g.Bs[0][1][ldsB]);
  gld_lds16(gBv, &sm.g.Bs[0][2][ldsB]);
  gA0 += 32; gA1 += 32; gBq += 32; gBk += 32; gBv += 32;
  __syncthreads();

  for (int t = 0; t < 32; ++t) {
    const int buf = t & 1;
    if (t < 31) {
      const int nb = buf ^ 1;
      gld_lds16(gA0, &sm.g.As[nb][ldsA0]);
      gld_lds16(gA1, &sm.g.As[nb][ldsA1]);
      gld_lds16(gBq, &sm.g.Bs[nb][0][ldsB]);
      gld_lds16(gBk, &sm.g.Bs[nb][1][ldsB]);
      gld_lds16(gBv, &sm.g.Bs[nb][2][ldsB]);
      gA0 += 32; gA1 += 32; gBq += 32; gBk += 32; gBv += 32;
    }
    bf16x8 af[4];
#pragma unroll
    for (int i = 0; i < 4; ++i) af[i] = *(const bf16x8*)&sm.g.As[buf][offA[i]];
#pragma unroll
    for (int z = 0; z < 3; ++z) {
      bf16x8 b0 = *(const bf16x8*)&sm.g.Bs[buf][z][offB[0]];
      bf16x8 b1 = *(const bf16x8*)&sm.g.Bs[buf][z][offB[1]];
#pragma unroll
      for (int i = 0; i < 4; ++i) {
        acc[z][i][0] = __builtin_amdgcn_mfma_f32_16x16x32_bf16(af[i], b0, acc[z][i][0], 0, 0, 0);
        acc[z][i][1] = __builtin_amdgcn_mfma_f32_16x16x32_bf16(af[i], b1, acc[z][i][1], 0, 0, 0);
      }
    }
    __syncthreads();
  }

  // ---- V epilogue: transpose in LDS, write Vt2[bh][d][s] coalesced
#pragma unroll
  for (int i = 0; i < 4; ++i)
#pragma unroll
    for (int r = 0; r < 4; ++r) {
      int ml = wr * 64 + i * 16 + kg * 4 + r;
#pragma unroll
      for (int j = 0; j < 2; ++j) {
        int nl = wc * 32 + j * 16 + ln;
        sm.Tt[nl][ml] = f2bf(acc[2][i][j][r]);
      }
    }
  __syncthreads();
  {
    const int b = m0 >> 11, s0 = m0 & 2047;
    unsigned short* vdst = Vt2 + ((size_t)(b * 16 + blockIdx.x) * 64) * NS + s0;
#pragma unroll
    for (int k = 0; k < 4; ++k) {
      int q = tid + k * 256;
      int row = q >> 4, off = q & 15;
      u16x8 v = *(const u16x8*)&sm.Tt[row][off * 8];
      *(u16x8*)(vdst + (size_t)row * NS + off * 8) = v;
    }
  }

  // ---- Q,K epilogue with fused RoPE (invf/sincos hoisted, shared across z)
  float invf[2];
#pragma unroll
  for (int j = 0; j < 2; ++j) {
    int n  = n0 + wc * 32 + j * 16 + ln;
    int ip = (n & 63) >> 1;
    invf[j] = __expf(-0.28782313662425572f * (float)ip);
  }
  const float SC_Q = 0.18033688011111543f;   // 0.125 * log2(e), folded into Q
#pragma unroll
  for (int i = 0; i < 4; ++i)
#pragma unroll
    for (int r = 0; r < 4; ++r) {
      int m = m0 + wr * 64 + i * 16 + kg * 4 + r;
      float pos = (float)tp[m];
#pragma unroll
      for (int j = 0; j < 2; ++j) {
        int n = n0 + wc * 32 + j * 16 + ln;
        float sn, cs;
        __sincosf(pos * invf[j], &sn, &cs);
#pragma unroll
        for (int z = 0; z < 2; ++z) {
          float v  = acc[z][i][j][r];
          float pv = __shfl_xor(v, 1);
          float outv = (n & 1) ? (pv * sn + v * cs) : (v * cs - pv * sn);
          if (z == 0) outv *= SC_Q;
          QKt[(size_t)z * NM * ND + (size_t)m * ND + n] = f2bf(outv);
        }
      }
    }
}

// ---------------------------------------------------------------- output GEMM
__global__ __launch_bounds__(256, 4) void gemm_out(
    const unsigned short* __restrict__ A,
    const unsigned short* __restrict__ Bw,
    float* __restrict__ C)
{
  __shared__ unsigned short As[2][128 * 32];
  __shared__ unsigned short Bs[2][128 * 32];

  const int tid  = threadIdx.x;
  const int wid  = tid >> 6, lane = tid & 63;
  const int ln   = lane & 15, kg = lane >> 4;
  const int wr   = wid >> 1,  wc = wid & 1;
  const int m0   = blockIdx.y * 128, n0 = blockIdx.x * 128;

  const int r0 = tid >> 2,        s0 = tid & 3;
  const int r1 = (tid + 256) >> 2;
  const int f0 = (r0 & 3) ^ ((r0 >> 2) & 3);
  const int f1 = (r1 & 3) ^ ((r1 >> 2) & 3);

  const unsigned short* gA0 = A  + (size_t)(m0 + r0) * ND + ((s0 ^ f0) * 8);
  const unsigned short* gA1 = A  + (size_t)(m0 + r1) * ND + ((s0 ^ f1) * 8);
  const unsigned short* gB0 = Bw + (size_t)(n0 + r0) * ND + ((s0 ^ f0) * 8);
  const unsigned short* gB1 = Bw + (size_t)(n0 + r1) * ND + ((s0 ^ f1) * 8);

  const int ldsO0 = wid * 512, ldsO1 = 2048 + wid * 512;

  const int fql = (ln & 3) ^ ((ln >> 2) & 3);
  int offA[4], offB[4];
#pragma unroll
  for (int i = 0; i < 4; ++i) {
    offA[i] = (wr * 64 + i * 16 + ln) * 32 + ((kg ^ fql) * 8);
    offB[i] = (wc * 64 + i * 16 + ln) * 32 + ((kg ^ fql) * 8);
  }

  f32x4 acc[4][4];
#pragma unroll
  for (int i = 0; i < 4; ++i)
#pragma unroll
    for (int j = 0; j < 4; ++j) acc[i][j] = (f32x4){0.f, 0.f, 0.f, 0.f};

  gld_lds16(gA0, &As[0][ldsO0]);
  gld_lds16(gA1, &As[0][ldsO1]);
  gld_lds16(gB0, &Bs[0][ldsO0]);
  gld_lds16(gB1, &Bs[0][ldsO1]);
  gA0 += 32; gA1 += 32; gB0 += 32; gB1 += 32;
  __syncthreads();

  for (int t = 0; t < 32; ++t) {
    const int buf = t & 1;
    if (t < 31) {
      const int nb = buf ^ 1;
      gld_lds16(gA0, &As[nb][ldsO0]);
      gld_lds16(gA1, &As[nb][ldsO1]);
      gld_lds16(gB0, &Bs[nb][ldsO0]);
      gld_lds16(gB1, &Bs[nb][ldsO1]);
      gA0 += 32; gA1 += 32; gB0 += 32; gB1 += 32;
    }
    bf16x8 af[4], bfr[4];
#pragma unroll
    for (int i = 0; i < 4; ++i) af[i] = *(const bf16x8*)&As[buf][offA[i]];
#pragma unroll
    for (int j = 0; j < 4; ++j) bfr[j] = *(const bf16x8*)&Bs[buf][offB[j]];
#pragma unroll
    for (int i = 0; i < 4; ++i)
#pragma unroll
      for (int j = 0; j < 4; ++j)
        acc[i][j] = __builtin_amdgcn_mfma_f32_16x16x32_bf16(af[i], bfr[j], acc[i][j], 0, 0, 0);
    __syncthreads();
  }

#pragma unroll
  for (int i = 0; i < 4; ++i)
#pragma unroll
    for (int j = 0; j < 4; ++j)
#pragma unroll
      for (int r = 0; r < 4; ++r) {
        int m = m0 + wr * 64 + i * 16 + kg * 4 + r;
        int n = n0 + wc * 64 + j * 16 + ln;
        C[(size_t)m * ND + n] = acc[i][j][r];
      }
}

// ---------------------------------------------------------------- flash attention
// 8 waves x 16 q-rows, 1024 WGs XCD-grouped, gld_lds dbuf K/V, row-sum via
// ones-MFMA, max3 tree, defer-max, exp2 domain (Q pre-scaled).
__global__ __launch_bounds__(512, 8) void attn_kernel(
    const unsigned short* __restrict__ Q,
    const unsigned short* __restrict__ K,
    const unsigned short* __restrict__ Vt2,
    unsigned short* __restrict__ O)
{
  __shared__ unsigned short Ks[2][64 * 64];
  __shared__ unsigned short Vs[2][64 * 64];
  __shared__ unsigned long long Pw[8][256];   // per-wave 2KB P/O staging

  const int tid = threadIdx.x;
  const int wid = tid >> 6, lane = tid & 63;
  const int ln  = lane & 15, kg = lane >> 4;

  const int flat = blockIdx.x;
  const int xcd  = flat & 7, g = flat >> 3;   // g in 0..127
  const int qb   = 15 - (g >> 3);             // 128-row q-block, longest first
  const int bh   = xcd + ((g & 7) << 3);      // bh % 8 == xcd
  const int b    = bh >> 4, h = bh & 15;

  const size_t base  = (size_t)b * NS * ND + (size_t)h * 64;
  const size_t vbase = (size_t)bh * 64 * NS;

  const int rA = tid >> 3, slA = tid & 7;
  const unsigned short* KgA = K + base + (size_t)rA * ND + ((slA ^ (rA & 7)) * 8);
  const unsigned short* VgA = Vt2 + vbase + (size_t)rA * NS + ((slA ^ (rA & 7)) * 8);
  const int ldsOff = tid * 8;

  char* pwb = (char*)&Pw[wid][0];
  int wb[4];
#pragma unroll
  for (int j = 0; j < 4; ++j)
    wb[j] = ln * 128 + (((2 * j + (kg >> 1)) ^ (ln & 7)) << 4) + ((kg & 1) << 3);
  const int rb0 = ln * 128 + ((kg ^ (ln & 7)) << 4);
  const int rb1 = ln * 128 + (((4 + kg) ^ (ln & 7)) << 4);

  const int nt   = 2 * qb + 2;
  const int q0   = qb * 128 + wid * 16;
  const int qrow = wid * 16 + ln;

  bf16x8 qf[2];
  {
    const unsigned short* qp = Q + base + (size_t)(q0 + ln) * ND + kg * 8;
    qf[0] = *(const bf16x8*)qp;
    qf[1] = *(const bf16x8*)(qp + 32);
  }

  bf16x8 onesf;
  {
    u16x8 t;
#pragma unroll
    for (int e = 0; e < 8; ++e) t[e] = 0x3F80;   // bf16 1.0
    onesf = __builtin_bit_cast(bf16x8, t);
  }

  float m_run = -1e30f;
  f32x4 acc_o[4];
  f32x4 acc_l = (f32x4){0.f, 0.f, 0.f, 0.f};   // ones-row MFMA: l = acc_l[0]
#pragma unroll
  for (int dj = 0; dj < 4; ++dj) acc_o[dj] = (f32x4){0.f, 0.f, 0.f, 0.f};

  gld_lds16(KgA, &Ks[0][ldsOff]);
  gld_lds16(VgA, &Vs[0][ldsOff]);
  __syncthreads();

  for (int t = 0; t < nt; ++t) {
    const int buf = t & 1;
    if (t + 1 < nt) {
      const size_t ko = (size_t)(t + 1) * 64 * ND;
      const int    vo = (t + 1) * 64;
      const int nb = buf ^ 1;
      gld_lds16(KgA + ko, &Ks[nb][ldsOff]);
      gld_lds16(VgA + vo, &Vs[nb][ldsOff]);
    }

    // ---- S^T = K·Q^T (exp2 domain)
    f32x4 st[4];
    __builtin_amdgcn_s_setprio(1);
#pragma unroll
    for (int j = 0; j < 4; ++j) {
      int kvr = j * 16 + ln;
      bf16x8 k0 = *(const bf16x8*)&Ks[buf][kvr * 64 + ((kg ^ (kvr & 7)) * 8)];
      bf16x8 k1 = *(const bf16x8*)&Ks[buf][kvr * 64 + (((4 + kg) ^ (kvr & 7)) * 8)];
      f32x4 z = (f32x4){0.f, 0.f, 0.f, 0.f};
      z = __builtin_amdgcn_mfma_f32_16x16x32_bf16(k0, qf[0], z, 0, 0, 0);
      z = __builtin_amdgcn_mfma_f32_16x16x32_bf16(k1, qf[1], z, 0, 0, 0);
      st[j] = z;
    }
    __builtin_amdgcn_s_setprio(0);

    const int trel = t - 2 * qb;
    if (trel >= 0) {
#pragma unroll
      for (int j = 0; j < 4; ++j)
#pragma unroll
        for (int r = 0; r < 4; ++r)
          if (trel * 64 + 16 * j + 4 * kg + r > qrow) st[j][r] = -1e30f;
    }

    // ---- row max via v_max3 tree
    float t1 = max3f(st[0][0], st[0][1], st[0][2]);
    float t2 = max3f(st[0][3], st[1][0], st[1][1]);
    float t3 = max3f(st[1][2], st[1][3], st[2][0]);
    float t4 = max3f(st[2][1], st[2][2], st[2][3]);
    float t5 = max3f(st[3][0], st[3][1], st[3][2]);
    float mx = fmaxf(max3f(t1, t2, t3), max3f(t4, t5, st[3][3]));
    mx = fmaxf(mx, __shfl_xor(mx, 16));
    mx = fmaxf(mx, __shfl_xor(mx, 32));

    // ---- defer-max rescale (applies to O and l accumulators)
    if (__any(mx > m_run + 11.0f)) {
      float mnew = fmaxf(m_run, mx);
      float alpha = EX2(m_run - mnew);
      m_run = mnew;
#pragma unroll
      for (int r = 0; r < 4; ++r) acc_l[r] *= alpha;
#pragma unroll
      for (int dj = 0; dj < 4; ++dj)
#pragma unroll
        for (int r = 0; r < 4; ++r) acc_o[dj][r] *= alpha;
    }

#pragma unroll
    for (int j = 0; j < 4; ++j)
#pragma unroll
      for (int r = 0; r < 4; ++r) st[j][r] = EX2(st[j][r] - m_run);

#pragma unroll
    for (int j = 0; j < 4; ++j) {
      unsigned w0 = cvtpk(st[j][0], st[j][1]);
      unsigned w1 = cvtpk(st[j][2], st[j][3]);
      *(unsigned long long*)(pwb + wb[j]) =
          (unsigned long long)w0 | ((unsigned long long)w1 << 32);
    }

    asm volatile("s_waitcnt lgkmcnt(0)" ::: "memory");
    __builtin_amdgcn_sched_barrier(0);

    bf16x8 pb0 = *(const bf16x8*)(pwb + rb0);
    bf16x8 pb1 = *(const bf16x8*)(pwb + rb1);
    __builtin_amdgcn_s_setprio(1);
#pragma unroll
    for (int dj = 0; dj < 4; ++dj) {
      int d = dj * 16 + ln;
      bf16x8 vb0 = *(const bf16x8*)&Vs[buf][d * 64 + ((kg ^ (d & 7)) * 8)];
      bf16x8 vb1 = *(const bf16x8*)&Vs[buf][d * 64 + (((4 + kg) ^ (d & 7)) * 8)];
      acc_o[dj] = __builtin_amdgcn_mfma_f32_16x16x32_bf16(vb0, pb0, acc_o[dj], 0, 0, 0);
      acc_o[dj] = __builtin_amdgcn_mfma_f32_16x16x32_bf16(vb1, pb1, acc_o[dj], 0, 0, 0);
    }
    // row-sum on the matrix pipe: every output row of (ones · P^T) = sum_kv P
    acc_l = __builtin_amdgcn_mfma_f32_16x16x32_bf16(onesf, pb0, acc_l, 0, 0, 0);
    acc_l = __builtin_amdgcn_mfma_f32_16x16x32_bf16(onesf, pb1, acc_l, 0, 0, 0);
    __builtin_amdgcn_s_setprio(0);
    __syncthreads();
  }

  asm volatile("s_waitcnt lgkmcnt(0)" ::: "memory");
  float inv = RCP(acc_l[0]);
#pragma unroll
  for (int dj = 0; dj < 4; ++dj) {
    unsigned w0 = cvtpk(acc_o[dj][0] * inv, acc_o[dj][1] * inv);
    unsigned w1 = cvtpk(acc_o[dj][2] * inv, acc_o[dj][3] * inv);
    *(unsigned long long*)(pwb + wb[dj]) =
        (unsigned long long)w0 | ((unsigned long long)w1 << 32);
  }
  asm volatile("s_waitcnt lgkmcnt(0)" ::: "memory");
  __builtin_amdgcn_sched_barrier(0);
  {
    const int orow = lane >> 3, og = lane & 7;
    const int lb = ((og ^ (orow & 7)) << 4);
    u16x8 o0 = *(const u16x8*)(pwb + orow * 128 + lb);
    u16x8 o1 = *(const u16x8*)(pwb + (8 + orow) * 128 + lb);
    *(u16x8*)(O + base + (size_t)(q0 + orow) * ND + og * 8) = o0;
    *(u16x8*)(O + base + (size_t)(q0 + 8 + orow) * ND + og * 8) = o1;
  }
}

// ---------------------------------------------------------------- launcher
extern "C" void kernel_launch(void* const* d_in, const int* in_sizes, int n_in,
                              void* d_out, int out_size, void* d_ws, size_t ws_size,
                              hipStream_t stream) {
  const float* x  = (const float*)d_in[0];
  const int*   tp = (const int*)d_in[1];
  const float* Wq = (const float*)d_in[2];
  const float* Wk = (const float*)d_in[3];
  const float* Wv = (const float*)d_in[4];
  const float* Wo = (const float*)d_in[5];
  float* out = (float*)d_out;

  const size_t MD2 = (size_t)NM * ND * 2;  // 16 MiB
  const size_t WW2 = (size_t)ND * ND * 2;  //  2 MiB
  char* w = (char*)d_ws;
  unsigned short* xb  = (unsigned short*)w; w += MD2;
  unsigned short* Qt  = (unsigned short*)w; w += MD2;   // Qt,Kt contiguous
  unsigned short* Kt  = (unsigned short*)w; w += MD2;
  unsigned short* Vt2 = (unsigned short*)w; w += MD2;
  unsigned short* Wqb = (unsigned short*)w; w += WW2;   // Wq,Wk,Wv contiguous
  unsigned short* Wkb = (unsigned short*)w; w += WW2;
  unsigned short* Wvb = (unsigned short*)w; w += WW2;
  unsigned short* Wob = (unsigned short*)w; w += WW2;
  unsigned short* Ot  = xb;  // alias: xb dead after gemm_qkv_fused

  cast_all<<<dim3(12288), 256, 0, stream>>>(x, Wq, Wk, Wv, Wo, xb, Wqb, Wkb, Wvb, Wob);
  gemm_qkv_fused<<<dim3(16, 64), 256, 0, stream>>>(xb, Wqb, tp, Qt, Vt2);
  attn_kernel<<<dim3(1024), 512, 0, stream>>>(Qt, Kt, Vt2, Ot);
  gemm_out<<<dim3(8, 64), 256, 0, stream>>>(Ot, Wob, out);
}